// Round 1
// baseline (2152.544 us; speedup 1.0000x reference)
//
#include <hip/hip_runtime.h>
#include <cstddef>

#define BATCH 4
#define NTOK 2048
#define NHEAD 16
#define DMODEL 1024
#define HD 64
#define MROWS (BATCH * NTOK)   // 8192

// ---------------------------------------------------------------------------
// GEMM: Y[m,o] = sum_k X[m,k] * W[o,k]   (Y = X @ W^T)
// M = 8192, N = K = 1024. blockIdx.z selects (Wk -> Kbuf) or (Wq -> Qbuf).
// 128x128 tile per block, 8x8 register blocking, TK=16.
// ---------------------------------------------------------------------------
__global__ __launch_bounds__(256) void gemm_xwT_kernel(
    const float* __restrict__ X,
    const float* __restrict__ Wk,
    const float* __restrict__ Wq,
    float* __restrict__ Kbuf,
    float* __restrict__ Qbuf) {
  const float* __restrict__ W = blockIdx.z ? Wq : Wk;
  float* __restrict__ Y = blockIdx.z ? Qbuf : Kbuf;

  __shared__ float As[128][17];
  __shared__ float Bs[128][17];

  const int tid = threadIdx.x;
  const int tx = tid & 15;   // 0..15 -> output col group
  const int ty = tid >> 4;   // 0..15 -> output row group
  const int m0 = blockIdx.x * 128;
  const int o0 = blockIdx.y * 128;

  float acc[8][8];
#pragma unroll
  for (int i = 0; i < 8; ++i)
#pragma unroll
    for (int j = 0; j < 8; ++j) acc[i][j] = 0.f;

  for (int k0 = 0; k0 < DMODEL; k0 += 16) {
    __syncthreads();
#pragma unroll
    for (int rep = 0; rep < 2; ++rep) {
      int f = tid + rep * 256;
      int r = f >> 2;            // 0..127
      int c = (f & 3) * 4;       // 0,4,8,12
      float4 a = *reinterpret_cast<const float4*>(&X[(size_t)(m0 + r) * DMODEL + k0 + c]);
      float4 b = *reinterpret_cast<const float4*>(&W[(size_t)(o0 + r) * DMODEL + k0 + c]);
      As[r][c + 0] = a.x; As[r][c + 1] = a.y; As[r][c + 2] = a.z; As[r][c + 3] = a.w;
      Bs[r][c + 0] = b.x; Bs[r][c + 1] = b.y; Bs[r][c + 2] = b.z; Bs[r][c + 3] = b.w;
    }
    __syncthreads();
#pragma unroll
    for (int kk = 0; kk < 16; ++kk) {
      float av[8], bv[8];
#pragma unroll
      for (int i = 0; i < 8; ++i) av[i] = As[i * 16 + ty][kk];
#pragma unroll
      for (int j = 0; j < 8; ++j) bv[j] = Bs[j * 16 + tx][kk];
#pragma unroll
      for (int i = 0; i < 8; ++i)
#pragma unroll
        for (int j = 0; j < 8; ++j) acc[i][j] += av[i] * bv[j];
    }
  }

#pragma unroll
  for (int i = 0; i < 8; ++i) {
    int m = m0 + i * 16 + ty;
#pragma unroll
    for (int j = 0; j < 8; ++j) {
      Y[(size_t)m * DMODEL + o0 + j * 16 + tx] = acc[i][j];
    }
  }
}

// ---------------------------------------------------------------------------
// Attention: for each row i of head (b,h):
//   s_j = K_i . Q_j   (j = 0..2047), w = softmax_j(s), out_i = sum_j w_j * K_j
// One thread per output row. K_i held in 64 VGPRs; j-tiles of Q and K staged
// in LDS (32 rows x 64). Online softmax (running max), acc in 64 VGPRs.
// Output written flat as (b,h,i,d) which equals the reference's reshape.
// ---------------------------------------------------------------------------
#define TJ 32

__global__ __launch_bounds__(256) void attn_kernel(
    const float* __restrict__ Kbuf,
    const float* __restrict__ Qbuf,
    float* __restrict__ out) {
  const int blk = blockIdx.x;
  const int itile = blk & 7;         // 2048 / 256 = 8 tiles of rows
  const int bh = blk >> 3;           // 0..63
  const int b = bh >> 4;
  const int h = bh & 15;
  const int tid = threadIdx.x;
  const int i = itile * 256 + tid;   // row within this head

  const float* __restrict__ Kh = Kbuf + (size_t)b * NTOK * DMODEL + h * HD;
  const float* __restrict__ Qh = Qbuf + (size_t)b * NTOK * DMODEL + h * HD;

  // K_i row into registers
  float ki[HD];
#pragma unroll
  for (int d4 = 0; d4 < 16; ++d4) {
    float4 v = *reinterpret_cast<const float4*>(&Kh[(size_t)i * DMODEL + d4 * 4]);
    ki[d4 * 4 + 0] = v.x; ki[d4 * 4 + 1] = v.y;
    ki[d4 * 4 + 2] = v.z; ki[d4 * 4 + 3] = v.w;
  }

  __shared__ float Qt[TJ][HD];
  __shared__ float Kt[TJ][HD];

  float m = -1e30f, l = 0.f;
  float acc[HD];
#pragma unroll
  for (int d = 0; d < HD; ++d) acc[d] = 0.f;

  for (int j0 = 0; j0 < NTOK; j0 += TJ) {
    __syncthreads();
    // stage TJ rows of Q and K: 2048 floats each, 2 float4 per thread per tile
#pragma unroll
    for (int rep = 0; rep < 2; ++rep) {
      int f = tid + rep * 256;
      int r = f >> 4;              // 0..31
      int c = (f & 15) * 4;        // 0..60
      *reinterpret_cast<float4*>(&Qt[r][c]) =
          *reinterpret_cast<const float4*>(&Qh[(size_t)(j0 + r) * DMODEL + c]);
      *reinterpret_cast<float4*>(&Kt[r][c]) =
          *reinterpret_cast<const float4*>(&Kh[(size_t)(j0 + r) * DMODEL + c]);
    }
    __syncthreads();

#pragma unroll 2
    for (int jj = 0; jj < TJ; ++jj) {
      // s = K_i . Q_{j0+jj}
      float s = 0.f;
#pragma unroll
      for (int d4 = 0; d4 < 16; ++d4) {
        float4 q = *reinterpret_cast<const float4*>(&Qt[jj][d4 * 4]);
        s += ki[d4 * 4 + 0] * q.x + ki[d4 * 4 + 1] * q.y +
             ki[d4 * 4 + 2] * q.z + ki[d4 * 4 + 3] * q.w;
      }
      if (s > m) {               // rare after warmup (~log(2048) times/row)
        float r = __expf(m - s);
        l *= r;
#pragma unroll
        for (int d = 0; d < HD; ++d) acc[d] *= r;
        m = s;
      }
      float w = __expf(s - m);
      l += w;
#pragma unroll
      for (int d4 = 0; d4 < 16; ++d4) {
        float4 kv = *reinterpret_cast<const float4*>(&Kt[jj][d4 * 4]);
        acc[d4 * 4 + 0] += w * kv.x;
        acc[d4 * 4 + 1] += w * kv.y;
        acc[d4 * 4 + 2] += w * kv.z;
        acc[d4 * 4 + 3] += w * kv.w;
      }
    }
  }

  const float inv = 1.f / l;
  // out flat (b,h,i,d)
  const size_t obase = (((size_t)bh) * NTOK + i) * HD;
#pragma unroll
  for (int d4 = 0; d4 < 16; ++d4) {
    float4 v = make_float4(acc[d4 * 4 + 0] * inv, acc[d4 * 4 + 1] * inv,
                           acc[d4 * 4 + 2] * inv, acc[d4 * 4 + 3] * inv);
    *reinterpret_cast<float4*>(&out[obase + d4 * 4]) = v;
  }
}

extern "C" void kernel_launch(void* const* d_in, const int* in_sizes, int n_in,
                              void* d_out, int out_size, void* d_ws, size_t ws_size,
                              hipStream_t stream) {
  const float* x  = (const float*)d_in[0];
  const float* Wk = (const float*)d_in[1];
  const float* Wq = (const float*)d_in[2];
  // d_in[3] (Wv) is dead code in the reference — never read.
  float* out = (float*)d_out;

  float* Kbuf = (float*)d_ws;                         // 8192*1024 f32 = 33.5 MB
  float* Qbuf = Kbuf + (size_t)MROWS * DMODEL;        // another 33.5 MB

  dim3 ggrid(MROWS / 128, DMODEL / 128, 2);           // (64, 8, 2)
  gemm_xwT_kernel<<<ggrid, 256, 0, stream>>>(x, Wk, Wq, Kbuf, Qbuf);

  dim3 agrid(BATCH * NHEAD * (NTOK / 256));           // 512
  attn_kernel<<<agrid, 256, 0, stream>>>(Kbuf, Qbuf, out);
}

// Round 3
// 520.463 us; speedup vs baseline: 4.1358x; 4.1358x over previous
//
#include <hip/hip_runtime.h>
#include <cstdint>
#include <cstddef>

#define NTOK 2048
#define DMODEL 1024
#define HD 64
#define MROWS 8192

using f16x8 = __attribute__((ext_vector_type(8))) _Float16;
using f16x4 = __attribute__((ext_vector_type(4))) _Float16;
using f32x4 = __attribute__((ext_vector_type(4))) float;
using u16x8 = __attribute__((ext_vector_type(8))) unsigned short;

// ---------------------------------------------------------------------------
// f32 -> f16 elementwise convert, 4 elems/thread
// ---------------------------------------------------------------------------
__global__ __launch_bounds__(256) void cvt_f32_f16(const float* __restrict__ in,
                                                   _Float16* __restrict__ out,
                                                   int n4) {
  int idx = blockIdx.x * 256 + threadIdx.x;
  if (idx < n4) {
    float4 v = reinterpret_cast<const float4*>(in)[idx];
    f16x4 o;
    o.x = (_Float16)v.x; o.y = (_Float16)v.y;
    o.z = (_Float16)v.z; o.w = (_Float16)v.w;
    reinterpret_cast<f16x4*>(out)[idx] = o;
  }
}

// ---------------------------------------------------------------------------
// f16 MFMA GEMM: Y[m][o] = sum_k X[m][k] * W[o][k]  (NT), Y stored f16.
// 128x128 tile, BK=32, 4 waves (2x2), 4x4 16x16 acc frags per wave,
// global_load_lds(16B) staging, double-buffered LDS, 2-phase sync.
// ---------------------------------------------------------------------------
#define GLDS16(g, l) __builtin_amdgcn_global_load_lds(                      \
    (const __attribute__((address_space(1))) void*)(g),                     \
    (__attribute__((address_space(3))) void*)(l), 16, 0, 0)

__global__ __launch_bounds__(256) void gemm_f16(
    const _Float16* __restrict__ X,
    const _Float16* __restrict__ Wk,
    const _Float16* __restrict__ Wq,
    _Float16* __restrict__ Kb,
    _Float16* __restrict__ Qb) {
  const _Float16* __restrict__ W = blockIdx.z ? Wq : Wk;
  _Float16* __restrict__ Y = blockIdx.z ? Qb : Kb;

  __shared__ _Float16 As[2][128 * 32];
  __shared__ _Float16 Bs[2][128 * 32];

  const int tid = threadIdx.x;
  const int lane = tid & 63;
  const int w = tid >> 6;
  const int m0 = blockIdx.x * 128;
  const int o0 = blockIdx.y * 128;

  // staging: wave w covers rows [w*32, w*32+32); LDS dest = uniform base + lane*16.
  const int srow = w * 32 + (lane >> 2);
  const int scol = (lane & 3) * 8;
  const _Float16* xsrc = X + (size_t)(m0 + srow) * DMODEL + scol;
  const _Float16* wsrc = W + (size_t)(o0 + srow) * DMODEL + scol;

  const int wr = w >> 1, wc = w & 1;
  const int arow = lane & 15, kg = lane >> 4;

  f32x4 zero = {0.f, 0.f, 0.f, 0.f};
  f32x4 acc[4][4];
#pragma unroll
  for (int mi = 0; mi < 4; ++mi)
#pragma unroll
    for (int ni = 0; ni < 4; ++ni) acc[mi][ni] = zero;

  // prologue stage into buf 0
  GLDS16(xsrc,               &As[0][(w * 32) * 32]);
  GLDS16(xsrc + 16 * DMODEL, &As[0][(w * 32 + 16) * 32]);
  GLDS16(wsrc,               &Bs[0][(w * 32) * 32]);
  GLDS16(wsrc + 16 * DMODEL, &Bs[0][(w * 32 + 16) * 32]);

  for (int kt = 0; kt < 32; ++kt) {
    __syncthreads();   // drains vmcnt -> buf[kt&1] fully staged
    if (kt + 1 < 32) {
      const int ko = (kt + 1) * 32;
      const int bn = (kt + 1) & 1;
      GLDS16(xsrc + ko,               &As[bn][(w * 32) * 32]);
      GLDS16(xsrc + ko + 16 * DMODEL, &As[bn][(w * 32 + 16) * 32]);
      GLDS16(wsrc + ko,               &Bs[bn][(w * 32) * 32]);
      GLDS16(wsrc + ko + 16 * DMODEL, &Bs[bn][(w * 32 + 16) * 32]);
    }
    const int buf = kt & 1;
    f16x8 af[4], bfr[4];
#pragma unroll
    for (int mi = 0; mi < 4; ++mi)
      af[mi] = *reinterpret_cast<const f16x8*>(
          &As[buf][(wr * 64 + mi * 16 + arow) * 32 + kg * 8]);
#pragma unroll
    for (int ni = 0; ni < 4; ++ni)
      bfr[ni] = *reinterpret_cast<const f16x8*>(
          &Bs[buf][(wc * 64 + ni * 16 + arow) * 32 + kg * 8]);
#pragma unroll
    for (int mi = 0; mi < 4; ++mi)
#pragma unroll
      for (int ni = 0; ni < 4; ++ni)
        acc[mi][ni] = __builtin_amdgcn_mfma_f32_16x16x32_f16(
            af[mi], bfr[ni], acc[mi][ni], 0, 0, 0);
  }

  // epilogue: C/D layout col=lane&15, row=(lane>>4)*4+r
#pragma unroll
  for (int mi = 0; mi < 4; ++mi) {
#pragma unroll
    for (int ni = 0; ni < 4; ++ni) {
#pragma unroll
      for (int r = 0; r < 4; ++r) {
        const int m = m0 + wr * 64 + mi * 16 + kg * 4 + r;
        const int o = o0 + wc * 64 + ni * 16 + arow;
        Y[(size_t)m * DMODEL + o] = (_Float16)acc[mi][ni][r];
      }
    }
  }
}

// ---------------------------------------------------------------------------
// Per-head transpose (dtype-agnostic 16-bit): KT[bh][d][i] = Kb[b*NTOK+i][h*64+d]
// ---------------------------------------------------------------------------
__global__ __launch_bounds__(256) void transpose_k(
    const unsigned short* __restrict__ Kb,
    unsigned short* __restrict__ KT) {
  const int blk = blockIdx.x;
  const int itile = blk & 31;
  const int bh = blk >> 5;
  const int b = bh >> 4, h = bh & 15;
  const int i0 = itile * 64;
  __shared__ unsigned short t[64][65];
  const int tid = threadIdx.x;
#pragma unroll
  for (int rr = 0; rr < 2; ++rr) {
    const int c = tid + rr * 256;
    const int i = c >> 3, d = (c & 7) * 8;
    u16x8 v = *reinterpret_cast<const u16x8*>(
        &Kb[(size_t)(b * NTOK + i0 + i) * DMODEL + h * HD + d]);
#pragma unroll
    for (int j = 0; j < 8; ++j) t[i][d + j] = v[j];
  }
  __syncthreads();
#pragma unroll
  for (int rr = 0; rr < 2; ++rr) {
    const int c = tid + rr * 256;
    const int d = c >> 3, ic = (c & 7) * 8;
    u16x8 v;
#pragma unroll
    for (int j = 0; j < 8; ++j) v[j] = t[ic + j][d];
    *reinterpret_cast<u16x8*>(&KT[((size_t)bh * HD + d) * NTOK + i0 + ic]) = v;
  }
}

// ---------------------------------------------------------------------------
// MFMA flash attention (f16 operands, f32 accumulate/softmax).
// Per wave: 16 i-rows. Per 32-j tile:
//   S(16x32) = K_i(16x64) . Q_j^T  -> 4 MFMA
//   online softmax over j (16-lane shfl_xor row reduce)
//   P -> f16 -> per-wave LDS [16][40] -> A-frag
//   O(16x64) += P(16x32) . K_j(32x64) -> 4 MFMA (B-frag from KT, j-contig)
// Output written flat (b,h,i,d) = the reference's reshape.
// ---------------------------------------------------------------------------
__global__ __launch_bounds__(256) void attn_mfma(
    const _Float16* __restrict__ Kb,
    const _Float16* __restrict__ Qb,
    const _Float16* __restrict__ KT,
    float* __restrict__ out) {
  const int bid = blockIdx.x;
  const int myid = (bid & 7) * 256 + (bid >> 3);  // XCD swizzle (2048%8==0, bijective)
  const int bh = myid >> 5;
  const int itile = myid & 31;
  const int b = bh >> 4, h = bh & 15;
  const int tid = threadIdx.x, lane = tid & 63, w = tid >> 6;
  const int i0 = itile * 64 + w * 16;
  const int col = lane & 15, kg = lane >> 4;

  const _Float16* Kh  = Kb + (size_t)b * NTOK * DMODEL + h * HD;
  const _Float16* Qh  = Qb + (size_t)b * NTOK * DMODEL + h * HD;
  const _Float16* KTh = KT + (size_t)bh * HD * NTOK;

  // A-frags of this wave's K_i tile: row=lane&15, k=(lane>>4)*8+e
  const f16x8 ak0 = *reinterpret_cast<const f16x8*>(
      &Kh[(size_t)(i0 + col) * DMODEL + kg * 8]);
  const f16x8 ak1 = *reinterpret_cast<const f16x8*>(
      &Kh[(size_t)(i0 + col) * DMODEL + 32 + kg * 8]);

  __shared__ _Float16 P[4][16 * 40];   // per-wave, rows padded to 40 (80B, 16B-aligned)
  _Float16* Pw = &P[w][0];

  f32x4 zero = {0.f, 0.f, 0.f, 0.f};
  f32x4 oacc[4];
#pragma unroll
  for (int dc = 0; dc < 4; ++dc) oacc[dc] = zero;
  float mr[4] = {-1e30f, -1e30f, -1e30f, -1e30f};
  float lsum[4] = {0.f, 0.f, 0.f, 0.f};

  for (int j0 = 0; j0 < NTOK; j0 += 32) {
    // ---- QK^T ----
    const _Float16* q0p = &Qh[(size_t)(j0 + col) * DMODEL + kg * 8];
    const _Float16* q1p = &Qh[(size_t)(j0 + 16 + col) * DMODEL + kg * 8];
    f16x8 q00 = *reinterpret_cast<const f16x8*>(q0p);
    f16x8 q01 = *reinterpret_cast<const f16x8*>(q0p + 32);
    f16x8 q10 = *reinterpret_cast<const f16x8*>(q1p);
    f16x8 q11 = *reinterpret_cast<const f16x8*>(q1p + 32);
    f32x4 s0 = zero, s1 = zero;
    s0 = __builtin_amdgcn_mfma_f32_16x16x32_f16(ak0, q00, s0, 0, 0, 0);
    s0 = __builtin_amdgcn_mfma_f32_16x16x32_f16(ak1, q01, s0, 0, 0, 0);
    s1 = __builtin_amdgcn_mfma_f32_16x16x32_f16(ak0, q10, s1, 0, 0, 0);
    s1 = __builtin_amdgcn_mfma_f32_16x16x32_f16(ak1, q11, s1, 0, 0, 0);

    // ---- online softmax over j; lane holds rows kg*4+r, cols col/col+16 ----
#pragma unroll
    for (int r = 0; r < 4; ++r) {
      float pm = fmaxf(s0[r], s1[r]);
      pm = fmaxf(pm, __shfl_xor(pm, 1));
      pm = fmaxf(pm, __shfl_xor(pm, 2));
      pm = fmaxf(pm, __shfl_xor(pm, 4));
      pm = fmaxf(pm, __shfl_xor(pm, 8));
      const float mn = fmaxf(mr[r], pm);
      const float sc = __expf(mr[r] - mn);
      mr[r] = mn;
      const float p0 = __expf(s0[r] - mn);
      const float p1 = __expf(s1[r] - mn);
      lsum[r] = lsum[r] * sc + p0 + p1;
      oacc[0][r] *= sc; oacc[1][r] *= sc; oacc[2][r] *= sc; oacc[3][r] *= sc;
      Pw[(kg * 4 + r) * 40 + col]      = (_Float16)p0;
      Pw[(kg * 4 + r) * 40 + 16 + col] = (_Float16)p1;
    }

    // ---- PV: A-frag of P (row=lane&15, k=j=kg*8+e), B-frag from KT ----
    f16x8 pa = *reinterpret_cast<const f16x8*>(&Pw[col * 40 + kg * 8]);
#pragma unroll
    for (int dc = 0; dc < 4; ++dc) {
      f16x8 kv = *reinterpret_cast<const f16x8*>(
          &KTh[(size_t)(dc * 16 + col) * NTOK + j0 + kg * 8]);
      oacc[dc] = __builtin_amdgcn_mfma_f32_16x16x32_f16(pa, kv, oacc[dc], 0, 0, 0);
    }
  }

  // ---- finalize: row-sum of lsum across the 16-lane group, scale, store ----
#pragma unroll
  for (int r = 0; r < 4; ++r) {
    float ls = lsum[r];
    ls += __shfl_xor(ls, 1);
    ls += __shfl_xor(ls, 2);
    ls += __shfl_xor(ls, 4);
    ls += __shfl_xor(ls, 8);
    const float inv = 1.0f / ls;
#pragma unroll
    for (int dc = 0; dc < 4; ++dc) {
      out[((size_t)bh * NTOK + i0 + kg * 4 + r) * HD + dc * 16 + col] =
          oacc[dc][r] * inv;
    }
  }
}

extern "C" void kernel_launch(void* const* d_in, const int* in_sizes, int n_in,
                              void* d_out, int out_size, void* d_ws, size_t ws_size,
                              hipStream_t stream) {
  const float* x  = (const float*)d_in[0];
  const float* Wk = (const float*)d_in[1];
  const float* Wq = (const float*)d_in[2];
  // d_in[3] (Wv) is dead code in the reference — never read.
  float* out = (float*)d_out;

  // ws layout (f16 elems): xb[8388608] | Wkb[1048576] | Wqb[1048576]
  //                        | Kb[8388608] | Qb[8388608]   = 54.5 MB
  // KT reuses xb's space (xb dead after GEMM).
  _Float16* xb  = (_Float16*)d_ws;
  _Float16* KT  = xb;
  _Float16* Wkb = xb + (size_t)8388608;
  _Float16* Wqb = Wkb + (size_t)1048576;
  _Float16* Kb  = Wqb + (size_t)1048576;
  _Float16* Qb  = Kb + (size_t)8388608;

  cvt_f32_f16<<<8192, 256, 0, stream>>>(x, xb, 2097152);
  cvt_f32_f16<<<1024, 256, 0, stream>>>(Wk, Wkb, 262144);
  cvt_f32_f16<<<1024, 256, 0, stream>>>(Wq, Wqb, 262144);

  dim3 ggrid(MROWS / 128, DMODEL / 128, 2);   // (64, 8, 2)
  gemm_f16<<<ggrid, 256, 0, stream>>>(xb, Wkb, Wqb, Kb, Qb);

  transpose_k<<<2048, 256, 0, stream>>>((const unsigned short*)Kb,
                                        (unsigned short*)KT);

  attn_mfma<<<2048, 256, 0, stream>>>(Kb, Qb, KT, out);
}

// Round 6
// 317.862 us; speedup vs baseline: 6.7719x; 1.6374x over previous
//
#include <hip/hip_runtime.h>
#include <cstdint>
#include <cstddef>

#define NTOK 2048
#define DMODEL 1024
#define HD 64
#define MROWS 8192

using f16x8  = __attribute__((ext_vector_type(8))) _Float16;
using f16x4  = __attribute__((ext_vector_type(4))) _Float16;
using f16x2  = __attribute__((ext_vector_type(2))) _Float16;
using f32x4  = __attribute__((ext_vector_type(4))) float;
using f32x16 = __attribute__((ext_vector_type(16))) float;
using u16x8  = __attribute__((ext_vector_type(8))) unsigned short;

#define Z16 {0.f,0.f,0.f,0.f,0.f,0.f,0.f,0.f,0.f,0.f,0.f,0.f,0.f,0.f,0.f,0.f}

// ---------------------------------------------------------------------------
// f32 -> f16 convert with optional scale (log2(e) folded into Wq)
// ---------------------------------------------------------------------------
__global__ __launch_bounds__(256) void cvt_f32_f16(const float* __restrict__ in,
                                                   _Float16* __restrict__ out,
                                                   int n4, float scale) {
  int idx = blockIdx.x * 256 + threadIdx.x;
  if (idx < n4) {
    float4 v = reinterpret_cast<const float4*>(in)[idx];
    f16x4 o;
    o.x = (_Float16)(v.x * scale); o.y = (_Float16)(v.y * scale);
    o.z = (_Float16)(v.z * scale); o.w = (_Float16)(v.w * scale);
    reinterpret_cast<f16x4*>(out)[idx] = o;
  }
}

// ---------------------------------------------------------------------------
// f16 MFMA GEMM: Y[m][o] = sum_k X[m][k] * W[o][k]  (NT), Y stored f16.
// 128x128 tile, BK=32, 4 waves, global_load_lds(16B), double-buffered.
// ---------------------------------------------------------------------------
#define GLDS16(g, l) __builtin_amdgcn_global_load_lds(                      \
    (const __attribute__((address_space(1))) void*)(g),                     \
    (__attribute__((address_space(3))) void*)(l), 16, 0, 0)

__global__ __launch_bounds__(256) void gemm_f16(
    const _Float16* __restrict__ X,
    const _Float16* __restrict__ Wk,
    const _Float16* __restrict__ Wq,
    _Float16* __restrict__ Kb,
    _Float16* __restrict__ Qb) {
  const _Float16* __restrict__ W = blockIdx.z ? Wq : Wk;
  _Float16* __restrict__ Y = blockIdx.z ? Qb : Kb;

  __shared__ _Float16 As[2][128 * 32];
  __shared__ _Float16 Bs[2][128 * 32];

  const int tid = threadIdx.x;
  const int lane = tid & 63;
  const int w = tid >> 6;
  const int m0 = blockIdx.x * 128;
  const int o0 = blockIdx.y * 128;

  const int srow = w * 32 + (lane >> 2);
  const int scol = (lane & 3) * 8;
  const _Float16* xsrc = X + (size_t)(m0 + srow) * DMODEL + scol;
  const _Float16* wsrc = W + (size_t)(o0 + srow) * DMODEL + scol;

  const int wr = w >> 1, wc = w & 1;
  const int arow = lane & 15, kg = lane >> 4;

  f32x4 zero = {0.f, 0.f, 0.f, 0.f};
  f32x4 acc[4][4];
#pragma unroll
  for (int mi = 0; mi < 4; ++mi)
#pragma unroll
    for (int ni = 0; ni < 4; ++ni) acc[mi][ni] = zero;

  GLDS16(xsrc,               &As[0][(w * 32) * 32]);
  GLDS16(xsrc + 16 * DMODEL, &As[0][(w * 32 + 16) * 32]);
  GLDS16(wsrc,               &Bs[0][(w * 32) * 32]);
  GLDS16(wsrc + 16 * DMODEL, &Bs[0][(w * 32 + 16) * 32]);

  for (int kt = 0; kt < 32; ++kt) {
    __syncthreads();
    if (kt + 1 < 32) {
      const int ko = (kt + 1) * 32;
      const int bn = (kt + 1) & 1;
      GLDS16(xsrc + ko,               &As[bn][(w * 32) * 32]);
      GLDS16(xsrc + ko + 16 * DMODEL, &As[bn][(w * 32 + 16) * 32]);
      GLDS16(wsrc + ko,               &Bs[bn][(w * 32) * 32]);
      GLDS16(wsrc + ko + 16 * DMODEL, &Bs[bn][(w * 32 + 16) * 32]);
    }
    const int buf = kt & 1;
    f16x8 af[4], bfr[4];
#pragma unroll
    for (int mi = 0; mi < 4; ++mi)
      af[mi] = *reinterpret_cast<const f16x8*>(
          &As[buf][(wr * 64 + mi * 16 + arow) * 32 + kg * 8]);
#pragma unroll
    for (int ni = 0; ni < 4; ++ni)
      bfr[ni] = *reinterpret_cast<const f16x8*>(
          &Bs[buf][(wc * 64 + ni * 16 + arow) * 32 + kg * 8]);
#pragma unroll
    for (int mi = 0; mi < 4; ++mi)
#pragma unroll
      for (int ni = 0; ni < 4; ++ni)
        acc[mi][ni] = __builtin_amdgcn_mfma_f32_16x16x32_f16(
            af[mi], bfr[ni], acc[mi][ni], 0, 0, 0);
  }

#pragma unroll
  for (int mi = 0; mi < 4; ++mi) {
#pragma unroll
    for (int ni = 0; ni < 4; ++ni) {
#pragma unroll
      for (int r = 0; r < 4; ++r) {
        const int m = m0 + wr * 64 + mi * 16 + kg * 4 + r;
        const int o = o0 + wc * 64 + ni * 16 + arow;
        Y[(size_t)m * DMODEL + o] = (_Float16)acc[mi][ni][r];
      }
    }
  }
}

// ---------------------------------------------------------------------------
// Per-head transpose: KT[bh][d][i] = Kb[b*NTOK+i][h*64+d]
// ---------------------------------------------------------------------------
__global__ __launch_bounds__(256) void transpose_k(
    const unsigned short* __restrict__ Kb,
    unsigned short* __restrict__ KT) {
  const int blk = blockIdx.x;
  const int itile = blk & 31;
  const int bh = blk >> 5;
  const int b = bh >> 4, h = bh & 15;
  const int i0 = itile * 64;
  __shared__ unsigned short t[64][65];
  const int tid = threadIdx.x;
#pragma unroll
  for (int rr = 0; rr < 2; ++rr) {
    const int c = tid + rr * 256;
    const int i = c >> 3, d = (c & 7) * 8;
    u16x8 v = *reinterpret_cast<const u16x8*>(
        &Kb[(size_t)(b * NTOK + i0 + i) * DMODEL + h * HD + d]);
#pragma unroll
    for (int j = 0; j < 8; ++j) t[i][d + j] = v[j];
  }
  __syncthreads();
#pragma unroll
  for (int rr = 0; rr < 2; ++rr) {
    const int c = tid + rr * 256;
    const int d = c >> 3, ic = (c & 7) * 8;
    u16x8 v;
#pragma unroll
    for (int j = 0; j < 8; ++j) v[j] = t[ic + j][d];
    *reinterpret_cast<u16x8*>(&KT[((size_t)bh * HD + d) * NTOK + i0 + ic]) = v;
  }
}

// ---------------------------------------------------------------------------
// Swapped-operand MFMA flash attention.
// Wave owns 32 i-rows. Per 64-j tile:
//   S^T = mfma_32x32x16(Q_j, K_i): lane holds col i=lane&31, 32 j's in regs
//   in-register softmax (fmax tree + __shfl_xor(.,32)), defer-max THR=8
//   P -> f16 -> per-wave LDS tile [32][68] -> PV A-frags
//   O += mfma_32x32x16(P, KT)   [O has col=d=lane&31, rows in regs]
// RESCALE NOTE: softmax state lives per-lane at row i=lane&31, but O's regs
// hold rows il=(r&3)+8*(r>>2)+4*hi. The rescale factor must be routed from
// lane il to this lane via per-wave LDS (r4/r5 bug: applied sc of row l31
// to row il -> 2^8-class blowup, matching the observed 1089 absmax).
// Scores pre-scaled by log2(e) (folded into Wq) -> exp2f.
// ---------------------------------------------------------------------------
__global__ __launch_bounds__(256) void attn_mfma(
    const _Float16* __restrict__ Kb,
    const _Float16* __restrict__ Qb,
    const _Float16* __restrict__ KT,
    float* __restrict__ out) {
  const int bid = blockIdx.x;
  const int myid = (bid & 7) * 128 + (bid >> 3);   // 1024 blocks, bijective
  const int bh = myid >> 4;                        // 16 blocks per head
  const int itile = myid & 15;
  const int b = bh >> 4, h = bh & 15;
  const int tid = threadIdx.x, lane = tid & 63, w = tid >> 6;
  const int l31 = lane & 31;
  const int hi = lane >> 5;
  const int hi8 = hi * 8;
  const int i0 = itile * 128 + w * 32;

  const _Float16* Kh  = Kb + (size_t)b * NTOK * DMODEL + h * HD;
  const _Float16* Qh  = Qb + (size_t)b * NTOK * DMODEL + h * HD;
  const _Float16* KTh = KT + (size_t)bh * HD * NTOK;

  // Per-wave P tile [i][j], j padded to 68 (2-way bank aliasing only)
  __shared__ _Float16 Pl[4][32][68];
  __shared__ float lsl[4][32];
  __shared__ float scl[4][32];   // per-row rescale factor broadcast line

  // Hoisted B-frags of K_i for QK^T: col=i=lane&31, k=d=ks*16+hi8+e
  f16x8 kbf[4];
#pragma unroll
  for (int ks = 0; ks < 4; ++ks)
    kbf[ks] = *reinterpret_cast<const f16x8*>(
        &Kh[(size_t)(i0 + l31) * DMODEL + ks * 16 + hi8]);

  f32x16 o0 = Z16, o1 = Z16;
  float mreg = -1e30f, ls = 0.f;

  for (int j0 = 0; j0 < NTOK; j0 += 64) {
    // ---- QK^T (swapped): A = Q rows j, B = K rows i ----
    f32x16 s0 = Z16, s1 = Z16;
    __builtin_amdgcn_s_setprio(1);
#pragma unroll
    for (int ks = 0; ks < 4; ++ks) {
      f16x8 qa0 = *reinterpret_cast<const f16x8*>(
          &Qh[(size_t)(j0 + l31) * DMODEL + ks * 16 + hi8]);
      f16x8 qa1 = *reinterpret_cast<const f16x8*>(
          &Qh[(size_t)(j0 + 32 + l31) * DMODEL + ks * 16 + hi8]);
      s0 = __builtin_amdgcn_mfma_f32_32x32x16_f16(qa0, kbf[ks], s0, 0, 0, 0);
      s1 = __builtin_amdgcn_mfma_f32_32x32x16_f16(qa1, kbf[ks], s1, 0, 0, 0);
    }
    __builtin_amdgcn_s_setprio(0);

    // ---- tile max for row i=l31 (16 j's here + 16 in partner half) ----
    float m0 = fmaxf(s0[0], s1[0]);
    float m1 = fmaxf(s0[1], s1[1]);
    float m2 = fmaxf(s0[2], s1[2]);
    float m3 = fmaxf(s0[3], s1[3]);
#pragma unroll
    for (int r = 4; r < 16; r += 4) {
      m0 = fmaxf(m0, fmaxf(s0[r], s1[r]));
      m1 = fmaxf(m1, fmaxf(s0[r + 1], s1[r + 1]));
      m2 = fmaxf(m2, fmaxf(s0[r + 2], s1[r + 2]));
      m3 = fmaxf(m3, fmaxf(s0[r + 3], s1[r + 3]));
    }
    float pm = fmaxf(fmaxf(m0, m1), fmaxf(m2, m3));
    pm = fmaxf(pm, __shfl_xor(pm, 32));

    // ---- defer-max rescale (rare, wave-uniform branch, per-row factors) ----
    if (!__all(pm <= mreg + 8.0f)) {
      const float mn = fmaxf(mreg, pm);
      const float sc = exp2f(mreg - mn);   // factor for ROW l31
      ls *= sc;
      mreg = mn;
      scl[w][l31] = sc;                    // both halves write same value
      // route per-row factor to the O-accumulator's reg-row mapping
#pragma unroll
      for (int r = 0; r < 16; ++r) {
        const int il = (r & 3) + 8 * (r >> 2) + 4 * hi;
        const float scr = scl[w][il];
        o0[r] *= scr; o1[r] *= scr;
      }
    }

    // ---- exp2 (scores pre-scaled by log2 e) ----
    float p0a[16], p1a[16];
#pragma unroll
    for (int r = 0; r < 16; ++r) {
      p0a[r] = exp2f(s0[r] - mreg);
      p1a[r] = exp2f(s1[r] - mreg);
    }
    float l0 = 0.f, l1 = 0.f, l2 = 0.f, l3 = 0.f;
#pragma unroll
    for (int r = 0; r < 16; r += 4) {
      l0 += p0a[r]     + p1a[r];
      l1 += p0a[r + 1] + p1a[r + 1];
      l2 += p0a[r + 2] + p1a[r + 2];
      l3 += p0a[r + 3] + p1a[r + 3];
    }
    ls += (l0 + l1) + (l2 + l3);

    // ---- P -> per-wave LDS tile (row i=l31, col j from the D-map) ----
#pragma unroll
    for (int r = 0; r < 16; r += 2) {
      const int j = (r & 3) + 8 * (r >> 2) + 4 * hi;  // j and j+1 are this r-pair
      f16x2 v0; v0.x = (_Float16)p0a[r]; v0.y = (_Float16)p0a[r + 1];
      *reinterpret_cast<f16x2*>(&Pl[w][l31][j]) = v0;
      f16x2 v1; v1.x = (_Float16)p1a[r]; v1.y = (_Float16)p1a[r + 1];
      *reinterpret_cast<f16x2*>(&Pl[w][l31][32 + j]) = v1;
    }

    // ---- PV: A-frag from own-wave LDS (row=i=l31, k=j), B-frag from KT ----
    __builtin_amdgcn_s_setprio(1);
#pragma unroll
    for (int ks = 0; ks < 4; ++ks) {
      f16x4 plo = *reinterpret_cast<const f16x4*>(&Pl[w][l31][ks * 16 + hi8]);
      f16x4 phi = *reinterpret_cast<const f16x4*>(&Pl[w][l31][ks * 16 + hi8 + 4]);
      f16x8 pa = __builtin_shufflevector(plo, phi, 0, 1, 2, 3, 4, 5, 6, 7);
      f16x8 kt0 = *reinterpret_cast<const f16x8*>(
          &KTh[(size_t)l31 * NTOK + j0 + ks * 16 + hi8]);
      f16x8 kt1 = *reinterpret_cast<const f16x8*>(
          &KTh[(size_t)(32 + l31) * NTOK + j0 + ks * 16 + hi8]);
      o0 = __builtin_amdgcn_mfma_f32_32x32x16_f16(pa, kt0, o0, 0, 0, 0);
      o1 = __builtin_amdgcn_mfma_f32_32x32x16_f16(pa, kt1, o1, 0, 0, 0);
    }
    __builtin_amdgcn_s_setprio(0);
  }

  // ---- finalize: combine lsum across lane halves, divide, store ----
  lsl[w][l31] = ls + __shfl_xor(ls, 32);
  __syncthreads();
#pragma unroll
  for (int r = 0; r < 16; ++r) {
    const int il = (r & 3) + 8 * (r >> 2) + 4 * hi;
    const float inv = 1.0f / lsl[w][il];
    const size_t rowb = ((size_t)bh * NTOK + i0 + il) * HD;
    out[rowb + l31]      = o0[r] * inv;
    out[rowb + 32 + l31] = o1[r] * inv;
  }
}

extern "C" void kernel_launch(void* const* d_in, const int* in_sizes, int n_in,
                              void* d_out, int out_size, void* d_ws, size_t ws_size,
                              hipStream_t stream) {
  const float* x  = (const float*)d_in[0];
  const float* Wk = (const float*)d_in[1];
  const float* Wq = (const float*)d_in[2];
  // d_in[3] (Wv) is dead code in the reference — never read.
  float* out = (float*)d_out;

  _Float16* xb  = (_Float16*)d_ws;
  _Float16* KT  = xb;                         // reuses xb after GEMM
  _Float16* Wkb = xb + (size_t)8388608;
  _Float16* Wqb = Wkb + (size_t)1048576;
  _Float16* Kb  = Wqb + (size_t)1048576;
  _Float16* Qb  = Kb + (size_t)8388608;

  cvt_f32_f16<<<8192, 256, 0, stream>>>(x, xb, 2097152, 1.0f);
  cvt_f32_f16<<<1024, 256, 0, stream>>>(Wk, Wkb, 262144, 1.0f);
  // log2(e) folded into Wq so softmax can use exp2 directly
  cvt_f32_f16<<<1024, 256, 0, stream>>>(Wq, Wqb, 262144, 1.4426950408889634f);

  dim3 ggrid(MROWS / 128, DMODEL / 128, 2);
  gemm_f16<<<ggrid, 256, 0, stream>>>(xb, Wkb, Wqb, Kb, Qb);

  transpose_k<<<2048, 256, 0, stream>>>((const unsigned short*)Kb,
                                        (unsigned short*)KT);

  attn_mfma<<<1024, 256, 0, stream>>>(Kb, Qb, KT, out);
}

// Round 7
// 302.394 us; speedup vs baseline: 7.1183x; 1.0512x over previous
//
#include <hip/hip_runtime.h>
#include <cstdint>
#include <cstddef>

#define NTOK 2048
#define DMODEL 1024
#define HD 64
#define MROWS 8192

using f16x8  = __attribute__((ext_vector_type(8))) _Float16;
using f16x4  = __attribute__((ext_vector_type(4))) _Float16;
using f16x2  = __attribute__((ext_vector_type(2))) _Float16;
using f32x4  = __attribute__((ext_vector_type(4))) float;
using f32x16 = __attribute__((ext_vector_type(16))) float;
using u16x8  = __attribute__((ext_vector_type(8))) unsigned short;
using u32x4  = __attribute__((ext_vector_type(4))) unsigned int;

#define Z16 {0.f,0.f,0.f,0.f,0.f,0.f,0.f,0.f,0.f,0.f,0.f,0.f,0.f,0.f,0.f,0.f}

__device__ __forceinline__ unsigned pkf16(float a, float b) {
  return __builtin_bit_cast(unsigned, __builtin_amdgcn_cvt_pkrtz(a, b));
}
__device__ __forceinline__ void plswap(unsigned &a, unsigned &b) {
  auto r = __builtin_amdgcn_permlane32_swap(a, b, false, false);
  a = r[0]; b = r[1];
}

// ---------------------------------------------------------------------------
// f32 -> f16 convert with optional scale (log2(e) folded into Wq)
// ---------------------------------------------------------------------------
__global__ __launch_bounds__(256) void cvt_f32_f16(const float* __restrict__ in,
                                                   _Float16* __restrict__ out,
                                                   int n4, float scale) {
  int idx = blockIdx.x * 256 + threadIdx.x;
  if (idx < n4) {
    float4 v = reinterpret_cast<const float4*>(in)[idx];
    f16x4 o;
    o.x = (_Float16)(v.x * scale); o.y = (_Float16)(v.y * scale);
    o.z = (_Float16)(v.z * scale); o.w = (_Float16)(v.w * scale);
    reinterpret_cast<f16x4*>(out)[idx] = o;
  }
}

// ---------------------------------------------------------------------------
// f16 MFMA GEMM: Y[m][o] = sum_k X[m][k] * W[o][k]  (NT), Y stored f16.
// ---------------------------------------------------------------------------
#define GLDS16(g, l) __builtin_amdgcn_global_load_lds(                      \
    (const __attribute__((address_space(1))) void*)(g),                     \
    (__attribute__((address_space(3))) void*)(l), 16, 0, 0)

__global__ __launch_bounds__(256) void gemm_f16(
    const _Float16* __restrict__ X,
    const _Float16* __restrict__ Wk,
    const _Float16* __restrict__ Wq,
    _Float16* __restrict__ Kb,
    _Float16* __restrict__ Qb) {
  const _Float16* __restrict__ W = blockIdx.z ? Wq : Wk;
  _Float16* __restrict__ Y = blockIdx.z ? Qb : Kb;

  __shared__ _Float16 As[2][128 * 32];
  __shared__ _Float16 Bs[2][128 * 32];

  const int tid = threadIdx.x;
  const int lane = tid & 63;
  const int w = tid >> 6;
  const int m0 = blockIdx.x * 128;
  const int o0 = blockIdx.y * 128;

  const int srow = w * 32 + (lane >> 2);
  const int scol = (lane & 3) * 8;
  const _Float16* xsrc = X + (size_t)(m0 + srow) * DMODEL + scol;
  const _Float16* wsrc = W + (size_t)(o0 + srow) * DMODEL + scol;

  const int wr = w >> 1, wc = w & 1;
  const int arow = lane & 15, kg = lane >> 4;

  f32x4 zero = {0.f, 0.f, 0.f, 0.f};
  f32x4 acc[4][4];
#pragma unroll
  for (int mi = 0; mi < 4; ++mi)
#pragma unroll
    for (int ni = 0; ni < 4; ++ni) acc[mi][ni] = zero;

  GLDS16(xsrc,               &As[0][(w * 32) * 32]);
  GLDS16(xsrc + 16 * DMODEL, &As[0][(w * 32 + 16) * 32]);
  GLDS16(wsrc,               &Bs[0][(w * 32) * 32]);
  GLDS16(wsrc + 16 * DMODEL, &Bs[0][(w * 32 + 16) * 32]);

  for (int kt = 0; kt < 32; ++kt) {
    __syncthreads();
    if (kt + 1 < 32) {
      const int ko = (kt + 1) * 32;
      const int bn = (kt + 1) & 1;
      GLDS16(xsrc + ko,               &As[bn][(w * 32) * 32]);
      GLDS16(xsrc + ko + 16 * DMODEL, &As[bn][(w * 32 + 16) * 32]);
      GLDS16(wsrc + ko,               &Bs[bn][(w * 32) * 32]);
      GLDS16(wsrc + ko + 16 * DMODEL, &Bs[bn][(w * 32 + 16) * 32]);
    }
    const int buf = kt & 1;
    f16x8 af[4], bfr[4];
#pragma unroll
    for (int mi = 0; mi < 4; ++mi)
      af[mi] = *reinterpret_cast<const f16x8*>(
          &As[buf][(wr * 64 + mi * 16 + arow) * 32 + kg * 8]);
#pragma unroll
    for (int ni = 0; ni < 4; ++ni)
      bfr[ni] = *reinterpret_cast<const f16x8*>(
          &Bs[buf][(wc * 64 + ni * 16 + arow) * 32 + kg * 8]);
#pragma unroll
    for (int mi = 0; mi < 4; ++mi)
#pragma unroll
      for (int ni = 0; ni < 4; ++ni)
        acc[mi][ni] = __builtin_amdgcn_mfma_f32_16x16x32_f16(
            af[mi], bfr[ni], acc[mi][ni], 0, 0, 0);
  }

#pragma unroll
  for (int mi = 0; mi < 4; ++mi) {
#pragma unroll
    for (int ni = 0; ni < 4; ++ni) {
#pragma unroll
      for (int r = 0; r < 4; ++r) {
        const int m = m0 + wr * 64 + mi * 16 + kg * 4 + r;
        const int o = o0 + wc * 64 + ni * 16 + arow;
        Y[(size_t)m * DMODEL + o] = (_Float16)acc[mi][ni][r];
      }
    }
  }
}

// ---------------------------------------------------------------------------
// Per-head transpose: KT[bh][d][i] = Kb[b*NTOK+i][h*64+d]
// ---------------------------------------------------------------------------
__global__ __launch_bounds__(256) void transpose_k(
    const unsigned short* __restrict__ Kb,
    unsigned short* __restrict__ KT) {
  const int blk = blockIdx.x;
  const int itile = blk & 31;
  const int bh = blk >> 5;
  const int b = bh >> 4, h = bh & 15;
  const int i0 = itile * 64;
  __shared__ unsigned short t[64][65];
  const int tid = threadIdx.x;
#pragma unroll
  for (int rr = 0; rr < 2; ++rr) {
    const int c = tid + rr * 256;
    const int i = c >> 3, d = (c & 7) * 8;
    u16x8 v = *reinterpret_cast<const u16x8*>(
        &Kb[(size_t)(b * NTOK + i0 + i) * DMODEL + h * HD + d]);
#pragma unroll
    for (int j = 0; j < 8; ++j) t[i][d + j] = v[j];
  }
  __syncthreads();
#pragma unroll
  for (int rr = 0; rr < 2; ++rr) {
    const int c = tid + rr * 256;
    const int d = c >> 3, ic = (c & 7) * 8;
    u16x8 v;
#pragma unroll
    for (int j = 0; j < 8; ++j) v[j] = t[ic + j][d];
    *reinterpret_cast<u16x8*>(&KT[((size_t)bh * HD + d) * NTOK + i0 + ic]) = v;
  }
}

// ---------------------------------------------------------------------------
// Swapped-operand MFMA flash attention, software-pipelined.
// Per 64-j tile: S^T = mfma(Q_j, K_i) [col=i]; in-register softmax
// (defer-max THR=8, per-row rescale routed via LDS scl line — r6 fix);
// P repacked IN-REGISTER via cvt_pkrtz + permlane32_swap (r4 path, proven
// equivalent to the LDS path by r4==r5 bit-identical outputs);
// O += mfma(P, KT) [col=d].
// Pipeline: Q loads prefetched one tile ahead (ping-pong reg sets);
// KT loads issued before softmax so its VALU hides their latency.
// ---------------------------------------------------------------------------
__global__ __launch_bounds__(256) void attn_mfma(
    const _Float16* __restrict__ Kb,
    const _Float16* __restrict__ Qb,
    const _Float16* __restrict__ KT,
    float* __restrict__ out) {
  const int bid = blockIdx.x;
  const int myid = (bid & 7) * 128 + (bid >> 3);   // 1024 blocks, bijective
  const int bh = myid >> 4;
  const int itile = myid & 15;
  const int b = bh >> 4, h = bh & 15;
  const int tid = threadIdx.x, lane = tid & 63, w = tid >> 6;
  const int l31 = lane & 31;
  const int hi = lane >> 5;
  const int hi8 = hi * 8;
  const int i0 = itile * 128 + w * 32;

  const _Float16* Kh  = Kb + (size_t)b * NTOK * DMODEL + h * HD;
  const _Float16* Qh  = Qb + (size_t)b * NTOK * DMODEL + h * HD;
  const _Float16* KTh = KT + (size_t)bh * HD * NTOK;

  __shared__ float lsl[4][32];
  __shared__ float scl[4][32];   // per-row rescale factor broadcast line

  // Hoisted B-frags of K_i for QK^T: col=i=lane&31, k=d=ks*16+hi8+e
  f16x8 kbf[4];
#pragma unroll
  for (int ks = 0; ks < 4; ++ks)
    kbf[ks] = *reinterpret_cast<const f16x8*>(
        &Kh[(size_t)(i0 + l31) * DMODEL + ks * 16 + hi8]);

  const _Float16* q0p  = &Qh[(size_t)l31 * DMODEL + hi8];
  const _Float16* q1p  = &Qh[(size_t)(32 + l31) * DMODEL + hi8];
  const _Float16* kt0p = &KTh[(size_t)l31 * NTOK + hi8];
  const _Float16* kt1p = &KTh[(size_t)(32 + l31) * NTOK + hi8];

  f32x16 o0 = Z16, o1 = Z16;
  float mreg = -1e30f, ls = 0.f;

  f16x8 qA0[4], qA1[4], qB0[4], qB1[4];
  // prologue: Q tile @ j0=0
#pragma unroll
  for (int ks = 0; ks < 4; ++ks) {
    qA0[ks] = *reinterpret_cast<const f16x8*>(q0p + ks * 16);
    qA1[ks] = *reinterpret_cast<const f16x8*>(q1p + ks * 16);
  }

#define PROCESS_TILE(Q0, Q1, JT)                                              \
  {                                                                           \
    f32x16 s0 = Z16, s1 = Z16;                                                \
    __builtin_amdgcn_s_setprio(1);                                            \
    _Pragma("unroll")                                                         \
    for (int ks = 0; ks < 4; ++ks) {                                          \
      s0 = __builtin_amdgcn_mfma_f32_32x32x16_f16(Q0[ks], kbf[ks], s0, 0,0,0);\
      s1 = __builtin_amdgcn_mfma_f32_32x32x16_f16(Q1[ks], kbf[ks], s1, 0,0,0);\
    }                                                                         \
    __builtin_amdgcn_s_setprio(0);                                            \
    /* KT loads for THIS tile: independent of softmax -> latency hidden */    \
    f16x8 kt0[4], kt1[4];                                                     \
    _Pragma("unroll")                                                         \
    for (int ks = 0; ks < 4; ++ks) {                                          \
      kt0[ks] = *reinterpret_cast<const f16x8*>(kt0p + (JT) + ks * 16);       \
      kt1[ks] = *reinterpret_cast<const f16x8*>(kt1p + (JT) + ks * 16);       \
    }                                                                         \
    /* row max (row i=l31: 16 j's here + 16 in partner half) */               \
    float m0 = fmaxf(s0[0], s1[0]);                                           \
    float m1 = fmaxf(s0[1], s1[1]);                                           \
    float m2 = fmaxf(s0[2], s1[2]);                                           \
    float m3 = fmaxf(s0[3], s1[3]);                                           \
    _Pragma("unroll")                                                         \
    for (int r = 4; r < 16; r += 4) {                                         \
      m0 = fmaxf(m0, fmaxf(s0[r], s1[r]));                                    \
      m1 = fmaxf(m1, fmaxf(s0[r + 1], s1[r + 1]));                            \
      m2 = fmaxf(m2, fmaxf(s0[r + 2], s1[r + 2]));                            \
      m3 = fmaxf(m3, fmaxf(s0[r + 3], s1[r + 3]));                            \
    }                                                                         \
    float pm = fmaxf(fmaxf(m0, m1), fmaxf(m2, m3));                           \
    pm = fmaxf(pm, __shfl_xor(pm, 32));                                       \
    /* defer-max rescale; factor routed row l31 -> reg-row il via LDS */      \
    if (!__all(pm <= mreg + 8.0f)) {                                          \
      const float mn = fmaxf(mreg, pm);                                       \
      const float sc = exp2f(mreg - mn);                                      \
      ls *= sc;                                                               \
      mreg = mn;                                                              \
      scl[w][l31] = sc;                                                       \
      _Pragma("unroll")                                                       \
      for (int r = 0; r < 16; ++r) {                                          \
        const int il = (r & 3) + 8 * (r >> 2) + 4 * hi;                       \
        const float scr = scl[w][il];                                         \
        o0[r] *= scr; o1[r] *= scr;                                           \
      }                                                                       \
    }                                                                         \
    float p0a[16], p1a[16];                                                   \
    _Pragma("unroll")                                                         \
    for (int r = 0; r < 16; ++r) {                                            \
      p0a[r] = exp2f(s0[r] - mreg);                                           \
      p1a[r] = exp2f(s1[r] - mreg);                                           \
    }                                                                         \
    float l0 = 0.f, l1 = 0.f, l2 = 0.f, l3 = 0.f;                             \
    _Pragma("unroll")                                                         \
    for (int r = 0; r < 16; r += 4) {                                         \
      l0 += p0a[r]     + p1a[r];                                              \
      l1 += p0a[r + 1] + p1a[r + 1];                                          \
      l2 += p0a[r + 2] + p1a[r + 2];                                          \
      l3 += p0a[r + 3] + p1a[r + 3];                                          \
    }                                                                         \
    ls += (l0 + l1) + (l2 + l3);                                              \
    /* in-register P repack (r4 path, proven by r4==r5) */                    \
    f16x8 pfr[4];                                                             \
    {                                                                         \
      unsigned a0 = pkf16(p0a[0], p0a[1]),  b0 = pkf16(p0a[4], p0a[5]);       \
      unsigned a1 = pkf16(p0a[2], p0a[3]),  b1 = pkf16(p0a[6], p0a[7]);       \
      plswap(a0, b0); plswap(a1, b1);                                         \
      u32x4 t; t[0] = a0; t[1] = a1; t[2] = b0; t[3] = b1;                    \
      pfr[0] = __builtin_bit_cast(f16x8, t);                                  \
      unsigned a2 = pkf16(p0a[8], p0a[9]),   b2 = pkf16(p0a[12], p0a[13]);    \
      unsigned a3 = pkf16(p0a[10], p0a[11]), b3 = pkf16(p0a[14], p0a[15]);    \
      plswap(a2, b2); plswap(a3, b3);                                         \
      t[0] = a2; t[1] = a3; t[2] = b2; t[3] = b3;                             \
      pfr[1] = __builtin_bit_cast(f16x8, t);                                  \
      unsigned a4 = pkf16(p1a[0], p1a[1]),  b4 = pkf16(p1a[4], p1a[5]);       \
      unsigned a5 = pkf16(p1a[2], p1a[3]),  b5 = pkf16(p1a[6], p1a[7]);       \
      plswap(a4, b4); plswap(a5, b5);                                         \
      t[0] = a4; t[1] = a5; t[2] = b4; t[3] = b5;                             \
      pfr[2] = __builtin_bit_cast(f16x8, t);                                  \
      unsigned a6 = pkf16(p1a[8], p1a[9]),   b6 = pkf16(p1a[12], p1a[13]);    \
      unsigned a7 = pkf16(p1a[10], p1a[11]), b7 = pkf16(p1a[14], p1a[15]);    \
      plswap(a6, b6); plswap(a7, b7);                                         \
      t[0] = a6; t[1] = a7; t[2] = b6; t[3] = b7;                             \
      pfr[3] = __builtin_bit_cast(f16x8, t);                                  \
    }                                                                         \
    __builtin_amdgcn_s_setprio(1);                                            \
    _Pragma("unroll")                                                         \
    for (int ks = 0; ks < 4; ++ks) {                                          \
      o0 = __builtin_amdgcn_mfma_f32_32x32x16_f16(pfr[ks], kt0[ks], o0, 0,0,0);\
      o1 = __builtin_amdgcn_mfma_f32_32x32x16_f16(pfr[ks], kt1[ks], o1, 0,0,0);\
    }                                                                         \
    __builtin_amdgcn_s_setprio(0);                                            \
  }

  for (int j0 = 0; j0 < NTOK; j0 += 128) {
    // prefetch tile B (j0+64) while processing tile A (j0)
#pragma unroll
    for (int ks = 0; ks < 4; ++ks) {
      qB0[ks] = *reinterpret_cast<const f16x8*>(
          q0p + (size_t)(j0 + 64) * DMODEL + ks * 16);
      qB1[ks] = *reinterpret_cast<const f16x8*>(
          q1p + (size_t)(j0 + 64) * DMODEL + ks * 16);
    }
    PROCESS_TILE(qA0, qA1, j0)
    // prefetch tile A for j0+128 while processing tile B
    if (j0 + 128 < NTOK) {
#pragma unroll
      for (int ks = 0; ks < 4; ++ks) {
        qA0[ks] = *reinterpret_cast<const f16x8*>(
            q0p + (size_t)(j0 + 128) * DMODEL + ks * 16);
        qA1[ks] = *reinterpret_cast<const f16x8*>(
            q1p + (size_t)(j0 + 128) * DMODEL + ks * 16);
      }
    }
    PROCESS_TILE(qB0, qB1, j0 + 64)
  }
#undef PROCESS_TILE

  // ---- finalize: combine lsum across lane halves, divide, store ----
  lsl[w][l31] = ls + __shfl_xor(ls, 32);
  __syncthreads();
#pragma unroll
  for (int r = 0; r < 16; ++r) {
    const int il = (r & 3) + 8 * (r >> 2) + 4 * hi;
    const float inv = 1.0f / lsl[w][il];
    const size_t rowb = ((size_t)bh * NTOK + i0 + il) * HD;
    out[rowb + l31]      = o0[r] * inv;
    out[rowb + 32 + l31] = o1[r] * inv;
  }
}

extern "C" void kernel_launch(void* const* d_in, const int* in_sizes, int n_in,
                              void* d_out, int out_size, void* d_ws, size_t ws_size,
                              hipStream_t stream) {
  const float* x  = (const float*)d_in[0];
  const float* Wk = (const float*)d_in[1];
  const float* Wq = (const float*)d_in[2];
  // d_in[3] (Wv) is dead code in the reference — never read.
  float* out = (float*)d_out;

  _Float16* xb  = (_Float16*)d_ws;
  _Float16* KT  = xb;                         // reuses xb after GEMM
  _Float16* Wkb = xb + (size_t)8388608;
  _Float16* Wqb = Wkb + (size_t)1048576;
  _Float16* Kb  = Wqb + (size_t)1048576;
  _Float16* Qb  = Kb + (size_t)8388608;

  cvt_f32_f16<<<8192, 256, 0, stream>>>(x, xb, 2097152, 1.0f);
  cvt_f32_f16<<<1024, 256, 0, stream>>>(Wk, Wkb, 262144, 1.0f);
  // log2(e) folded into Wq so softmax can use exp2 directly
  cvt_f32_f16<<<1024, 256, 0, stream>>>(Wq, Wqb, 262144, 1.4426950408889634f);

  dim3 ggrid(MROWS / 128, DMODEL / 128, 2);
  gemm_f16<<<ggrid, 256, 0, stream>>>(xb, Wkb, Wqb, Kb, Qb);

  transpose_k<<<2048, 256, 0, stream>>>((const unsigned short*)Kb,
                                        (unsigned short*)KT);

  attn_mfma<<<1024, 256, 0, stream>>>(Kb, Qb, KT, out);
}

// Round 8
// 192.994 us; speedup vs baseline: 11.1534x; 1.5669x over previous
//
#include <hip/hip_runtime.h>
#include <cstdint>
#include <cstddef>

#define NTOK 2048
#define DMODEL 1024
#define HD 64
#define MROWS 8192

using f16x8  = __attribute__((ext_vector_type(8))) _Float16;
using f16x4  = __attribute__((ext_vector_type(4))) _Float16;
using f32x4  = __attribute__((ext_vector_type(4))) float;
using f32x16 = __attribute__((ext_vector_type(16))) float;
using u16x8  = __attribute__((ext_vector_type(8))) unsigned short;
using u32x4  = __attribute__((ext_vector_type(4))) unsigned int;

#define Z16 {0.f,0.f,0.f,0.f,0.f,0.f,0.f,0.f,0.f,0.f,0.f,0.f,0.f,0.f,0.f,0.f}

__device__ __forceinline__ unsigned pkf16(float a, float b) {
  return __builtin_bit_cast(unsigned, __builtin_amdgcn_cvt_pkrtz(a, b));
}
__device__ __forceinline__ void plswap(unsigned &a, unsigned &b) {
  auto r = __builtin_amdgcn_permlane32_swap(a, b, false, false);
  a = r[0]; b = r[1];
}
// raw v_exp_f32: args here are always <= 0 and flush-to-zero below -126 is
// the mathematically right answer for softmax tails.
__device__ __forceinline__ float fexp2(float x) {
  return __builtin_amdgcn_exp2f(x);
}

// ---------------------------------------------------------------------------
// f32 -> f16 convert with optional scale (log2(e) folded into Wq)
// ---------------------------------------------------------------------------
__global__ __launch_bounds__(256) void cvt_f32_f16(const float* __restrict__ in,
                                                   _Float16* __restrict__ out,
                                                   int n4, float scale) {
  int idx = blockIdx.x * 256 + threadIdx.x;
  if (idx < n4) {
    float4 v = reinterpret_cast<const float4*>(in)[idx];
    f16x4 o;
    o.x = (_Float16)(v.x * scale); o.y = (_Float16)(v.y * scale);
    o.z = (_Float16)(v.z * scale); o.w = (_Float16)(v.w * scale);
    reinterpret_cast<f16x4*>(out)[idx] = o;
  }
}

// ---------------------------------------------------------------------------
// f16 MFMA GEMM: Y[m][o] = sum_k X[m][k] * W[o][k]  (NT), Y stored f16.
// ---------------------------------------------------------------------------
#define GLDS16(g, l) __builtin_amdgcn_global_load_lds(                      \
    (const __attribute__((address_space(1))) void*)(g),                     \
    (__attribute__((address_space(3))) void*)(l), 16, 0, 0)

__global__ __launch_bounds__(256) void gemm_f16(
    const _Float16* __restrict__ X,
    const _Float16* __restrict__ Wk,
    const _Float16* __restrict__ Wq,
    _Float16* __restrict__ Kb,
    _Float16* __restrict__ Qb) {
  const _Float16* __restrict__ W = blockIdx.z ? Wq : Wk;
  _Float16* __restrict__ Y = blockIdx.z ? Qb : Kb;

  __shared__ _Float16 As[2][128 * 32];
  __shared__ _Float16 Bs[2][128 * 32];

  const int tid = threadIdx.x;
  const int lane = tid & 63;
  const int w = tid >> 6;
  const int m0 = blockIdx.x * 128;
  const int o0 = blockIdx.y * 128;

  const int srow = w * 32 + (lane >> 2);
  const int scol = (lane & 3) * 8;
  const _Float16* xsrc = X + (size_t)(m0 + srow) * DMODEL + scol;
  const _Float16* wsrc = W + (size_t)(o0 + srow) * DMODEL + scol;

  const int wr = w >> 1, wc = w & 1;
  const int arow = lane & 15, kg = lane >> 4;

  f32x4 zero = {0.f, 0.f, 0.f, 0.f};
  f32x4 acc[4][4];
#pragma unroll
  for (int mi = 0; mi < 4; ++mi)
#pragma unroll
    for (int ni = 0; ni < 4; ++ni) acc[mi][ni] = zero;

  GLDS16(xsrc,               &As[0][(w * 32) * 32]);
  GLDS16(xsrc + 16 * DMODEL, &As[0][(w * 32 + 16) * 32]);
  GLDS16(wsrc,               &Bs[0][(w * 32) * 32]);
  GLDS16(wsrc + 16 * DMODEL, &Bs[0][(w * 32 + 16) * 32]);

  for (int kt = 0; kt < 32; ++kt) {
    __syncthreads();
    if (kt + 1 < 32) {
      const int ko = (kt + 1) * 32;
      const int bn = (kt + 1) & 1;
      GLDS16(xsrc + ko,               &As[bn][(w * 32) * 32]);
      GLDS16(xsrc + ko + 16 * DMODEL, &As[bn][(w * 32 + 16) * 32]);
      GLDS16(wsrc + ko,               &Bs[bn][(w * 32) * 32]);
      GLDS16(wsrc + ko + 16 * DMODEL, &Bs[bn][(w * 32 + 16) * 32]);
    }
    const int buf = kt & 1;
    f16x8 af[4], bfr[4];
#pragma unroll
    for (int mi = 0; mi < 4; ++mi)
      af[mi] = *reinterpret_cast<const f16x8*>(
          &As[buf][(wr * 64 + mi * 16 + arow) * 32 + kg * 8]);
#pragma unroll
    for (int ni = 0; ni < 4; ++ni)
      bfr[ni] = *reinterpret_cast<const f16x8*>(
          &Bs[buf][(wc * 64 + ni * 16 + arow) * 32 + kg * 8]);
#pragma unroll
    for (int mi = 0; mi < 4; ++mi)
#pragma unroll
      for (int ni = 0; ni < 4; ++ni)
        acc[mi][ni] = __builtin_amdgcn_mfma_f32_16x16x32_f16(
            af[mi], bfr[ni], acc[mi][ni], 0, 0, 0);
  }

#pragma unroll
  for (int mi = 0; mi < 4; ++mi) {
#pragma unroll
    for (int ni = 0; ni < 4; ++ni) {
#pragma unroll
      for (int r = 0; r < 4; ++r) {
        const int m = m0 + wr * 64 + mi * 16 + kg * 4 + r;
        const int o = o0 + wc * 64 + ni * 16 + arow;
        Y[(size_t)m * DMODEL + o] = (_Float16)acc[mi][ni][r];
      }
    }
  }
}

// ---------------------------------------------------------------------------
// pack_rows: Src ([8192][1024] f16, head-interleaved) -> fragment-ordered
// Pk[bh][rt(64 tiles of 32 rows)][ks(4)][lane(64)][8]:
//   entry(rt,ks,l,e) = Src_head[rt*32 + (l&31)][ks*16 + (l>>5)*8 + e]
// so attention's QK A-frag / kbf load is lane -> base + lane*16B (coalesced).
// Stages a 64x64 tile through padded LDS; both phases coalesced.
// ---------------------------------------------------------------------------
__global__ __launch_bounds__(256) void pack_rows(
    const _Float16* __restrict__ Src,
    _Float16* __restrict__ Pk) {
  const int blk = blockIdx.x;
  const int bh = blk >> 5;           // 64
  const int rt64 = blk & 31;         // 32 tiles of 64 rows
  const int b = bh >> 4, h = bh & 15;
  const int tid = threadIdx.x;

  __shared__ _Float16 t[64][72];     // rows 144B (16B-aligned), pad kills conflicts
#pragma unroll
  for (int rr = 0; rr < 2; ++rr) {
    const int c = tid + rr * 256;
    const int jr = c >> 3, dcol = (c & 7) * 8;
    *reinterpret_cast<f16x8*>(&t[jr][dcol]) =
        *reinterpret_cast<const f16x8*>(
            &Src[(size_t)(b * NTOK + rt64 * 64 + jr) * DMODEL + h * HD + dcol]);
  }
  __syncthreads();
#pragma unroll
  for (int rr = 0; rr < 2; ++rr) {
    const int cI = tid + rr * 256;   // (rs,ks,l)
    const int rs = cI >> 8, ks = (cI >> 6) & 3, l = cI & 63;
    f16x8 v = *reinterpret_cast<const f16x8*>(
        &t[rs * 32 + (l & 31)][ks * 16 + (l >> 5) * 8]);
    const size_t ch = ((size_t)(bh * 64 + rt64 * 2 + rs) * 4 + ks) * 512 + l * 8;
    *reinterpret_cast<f16x8*>(&Pk[ch]) = v;
  }
}

// ---------------------------------------------------------------------------
// pack_kt: Kb -> transposed fragment-ordered
// KTp[bh][jt(32 tiles of 64 j)][ds(2)][ks(4)][lane(64)][8]:
//   entry(jt,ds,ks,l,e) = K_head[jt*64 + ks*16 + (l>>5)*8 + e][ds*32 + (l&31)]
// = the PV B-frag. Stages K rows through LDS, gathers columns.
// ---------------------------------------------------------------------------
__global__ __launch_bounds__(256) void pack_kt(
    const _Float16* __restrict__ Kb,
    _Float16* __restrict__ KTp) {
  const int blk = blockIdx.x;
  const int bh = blk >> 5;
  const int jt = blk & 31;
  const int b = bh >> 4, h = bh & 15;
  const int tid = threadIdx.x;

  __shared__ _Float16 t[64][72];
#pragma unroll
  for (int rr = 0; rr < 2; ++rr) {
    const int c = tid + rr * 256;
    const int jr = c >> 3, dcol = (c & 7) * 8;
    *reinterpret_cast<f16x8*>(&t[jr][dcol]) =
        *reinterpret_cast<const f16x8*>(
            &Kb[(size_t)(b * NTOK + jt * 64 + jr) * DMODEL + h * HD + dcol]);
  }
  __syncthreads();
#pragma unroll
  for (int rr = 0; rr < 2; ++rr) {
    const int cI = tid + rr * 256;   // (ds,ks,l)
    const int ds = cI >> 8, ks = (cI >> 6) & 3, l = cI & 63;
    const int col = ds * 32 + (l & 31);
    const int row0 = ks * 16 + (l >> 5) * 8;
    f16x8 v;
#pragma unroll
    for (int e = 0; e < 8; ++e) v[e] = t[row0 + e][col];
    const size_t ch = (((size_t)(bh * 32 + jt) * 2 + ds) * 4 + ks) * 512 + l * 8;
    *reinterpret_cast<f16x8*>(&KTp[ch]) = v;
  }
}

// ---------------------------------------------------------------------------
// Swapped-operand MFMA flash attention, software-pipelined, PACKED operands.
// All per-tile loads are lane -> base + lane*16B (fully coalesced 1KB/instr).
// Per 64-j tile: S^T = mfma(Q_j, K_i) [col=i]; in-register softmax
// (defer-max THR=8, per-row rescale routed via LDS scl line — r6 fix);
// P repacked in-register via cvt_pkrtz + permlane32_swap; O += mfma(P, KT).
// ---------------------------------------------------------------------------
__global__ __launch_bounds__(256) void attn_mfma(
    const _Float16* __restrict__ Kb,
    const _Float16* __restrict__ Qp,
    const _Float16* __restrict__ KTp,
    float* __restrict__ out) {
  const int bid = blockIdx.x;
  const int myid = (bid & 7) * 128 + (bid >> 3);   // 1024 blocks, bijective
  const int bh = myid >> 4;
  const int itile = myid & 15;
  const int b = bh >> 4, h = bh & 15;
  const int tid = threadIdx.x, lane = tid & 63, w = tid >> 6;
  const int l31 = lane & 31;
  const int hi = lane >> 5;
  const int hi8 = hi * 8;
  const int i0 = itile * 128 + w * 32;

  const _Float16* Kh   = Kb + (size_t)b * NTOK * DMODEL + h * HD;
  const _Float16* qpp  = Qp  + (size_t)bh * 131072 + lane * 8;   // 64*4*512
  const _Float16* ktpp = KTp + (size_t)bh * 131072 + lane * 8;   // 32*2*4*512

  __shared__ float lsl[4][32];
  __shared__ float scl[4][32];   // per-row rescale factor broadcast line

  // kbf: one-time per wave, read from row-major Kb (uncoalesced but tiny)
  f16x8 kbf[4];
#pragma unroll
  for (int ks = 0; ks < 4; ++ks)
    kbf[ks] = *reinterpret_cast<const f16x8*>(
        &Kh[(size_t)(i0 + l31) * DMODEL + ks * 16 + hi8]);

  f32x16 o0 = Z16, o1 = Z16;
  float mreg = -1e30f, ls = 0.f;

  f16x8 qA0[4], qA1[4], qB0[4], qB1[4];
#pragma unroll
  for (int ks = 0; ks < 4; ++ks) {           // prologue: jt = 0
    qA0[ks] = *reinterpret_cast<const f16x8*>(qpp + (size_t)ks * 512);
    qA1[ks] = *reinterpret_cast<const f16x8*>(qpp + (size_t)(4 + ks) * 512);
  }

#define PROCESS_TILE(Q0, Q1, JT)                                              \
  {                                                                           \
    f32x16 s0 = Z16, s1 = Z16;                                                \
    __builtin_amdgcn_s_setprio(1);                                            \
    _Pragma("unroll")                                                         \
    for (int ks = 0; ks < 4; ++ks) {                                          \
      s0 = __builtin_amdgcn_mfma_f32_32x32x16_f16(Q0[ks], kbf[ks], s0, 0,0,0);\
      s1 = __builtin_amdgcn_mfma_f32_32x32x16_f16(Q1[ks], kbf[ks], s1, 0,0,0);\
    }                                                                         \
    __builtin_amdgcn_s_setprio(0);                                            \
    /* KT loads for THIS tile: independent of softmax -> latency hidden */    \
    f16x8 kt0[4], kt1[4];                                                     \
    _Pragma("unroll")                                                         \
    for (int ks = 0; ks < 4; ++ks) {                                          \
      kt0[ks] = *reinterpret_cast<const f16x8*>(                              \
          ktpp + ((size_t)(JT) * 8 + ks) * 512);                              \
      kt1[ks] = *reinterpret_cast<const f16x8*>(                              \
          ktpp + ((size_t)(JT) * 8 + 4 + ks) * 512);                          \
    }                                                                         \
    float m0 = fmaxf(s0[0], s1[0]);                                           \
    float m1 = fmaxf(s0[1], s1[1]);                                           \
    float m2 = fmaxf(s0[2], s1[2]);                                           \
    float m3 = fmaxf(s0[3], s1[3]);                                           \
    _Pragma("unroll")                                                         \
    for (int r = 4; r < 16; r += 4) {                                         \
      m0 = fmaxf(m0, fmaxf(s0[r], s1[r]));                                    \
      m1 = fmaxf(m1, fmaxf(s0[r + 1], s1[r + 1]));                            \
      m2 = fmaxf(m2, fmaxf(s0[r + 2], s1[r + 2]));                            \
      m3 = fmaxf(m3, fmaxf(s0[r + 3], s1[r + 3]));                            \
    }                                                                         \
    float pm = fmaxf(fmaxf(m0, m1), fmaxf(m2, m3));                           \
    pm = fmaxf(pm, __shfl_xor(pm, 32));                                       \
    if (!__all(pm <= mreg + 8.0f)) {                                          \
      const float mn = fmaxf(mreg, pm);                                       \
      const float sc = fexp2(mreg - mn);                                      \
      ls *= sc;                                                               \
      mreg = mn;                                                              \
      scl[w][l31] = sc;                                                       \
      _Pragma("unroll")                                                       \
      for (int r = 0; r < 16; ++r) {                                          \
        const int il = (r & 3) + 8 * (r >> 2) + 4 * hi;                       \
        const float scr = scl[w][il];                                         \
        o0[r] *= scr; o1[r] *= scr;                                           \
      }                                                                       \
    }                                                                         \
    float p0a[16], p1a[16];                                                   \
    _Pragma("unroll")                                                         \
    for (int r = 0; r < 16; ++r) {                                            \
      p0a[r] = fexp2(s0[r] - mreg);                                           \
      p1a[r] = fexp2(s1[r] - mreg);                                           \
    }                                                                         \
    float l0 = 0.f, l1 = 0.f, l2 = 0.f, l3 = 0.f;                             \
    _Pragma("unroll")                                                         \
    for (int r = 0; r < 16; r += 4) {                                         \
      l0 += p0a[r]     + p1a[r];                                              \
      l1 += p0a[r + 1] + p1a[r + 1];                                          \
      l2 += p0a[r + 2] + p1a[r + 2];                                          \
      l3 += p0a[r + 3] + p1a[r + 3];                                          \
    }                                                                         \
    ls += (l0 + l1) + (l2 + l3);                                              \
    f16x8 pfr[4];                                                             \
    {                                                                         \
      unsigned a0 = pkf16(p0a[0], p0a[1]),  b0 = pkf16(p0a[4], p0a[5]);       \
      unsigned a1 = pkf16(p0a[2], p0a[3]),  b1 = pkf16(p0a[6], p0a[7]);       \
      plswap(a0, b0); plswap(a1, b1);                                         \
      u32x4 t; t[0] = a0; t[1] = a1; t[2] = b0; t[3] = b1;                    \
      pfr[0] = __builtin_bit_cast(f16x8, t);                                  \
      unsigned a2 = pkf16(p0a[8], p0a[9]),   b2 = pkf16(p0a[12], p0a[13]);    \
      unsigned a3 = pkf16(p0a[10], p0a[11]), b3 = pkf16(p0a[14], p0a[15]);    \
      plswap(a2, b2); plswap(a3, b3);                                         \
      t[0] = a2; t[1] = a3; t[2] = b2; t[3] = b3;                             \
      pfr[1] = __builtin_bit_cast(f16x8, t);                                  \
      unsigned a4 = pkf16(p1a[0], p1a[1]),  b4 = pkf16(p1a[4], p1a[5]);       \
      unsigned a5 = pkf16(p1a[2], p1a[3]),  b5 = pkf16(p1a[6], p1a[7]);       \
      plswap(a4, b4); plswap(a5, b5);                                         \
      t[0] = a4; t[1] = a5; t[2] = b4; t[3] = b5;                             \
      pfr[2] = __builtin_bit_cast(f16x8, t);                                  \
      unsigned a6 = pkf16(p1a[8], p1a[9]),   b6 = pkf16(p1a[12], p1a[13]);    \
      unsigned a7 = pkf16(p1a[10], p1a[11]), b7 = pkf16(p1a[14], p1a[15]);    \
      plswap(a6, b6); plswap(a7, b7);                                         \
      t[0] = a6; t[1] = a7; t[2] = b6; t[3] = b7;                             \
      pfr[3] = __builtin_bit_cast(f16x8, t);                                  \
    }                                                                         \
    __builtin_amdgcn_s_setprio(1);                                            \
    _Pragma("unroll")                                                         \
    for (int ks = 0; ks < 4; ++ks) {                                          \
      o0 = __builtin_amdgcn_mfma_f32_32x32x16_f16(pfr[ks], kt0[ks], o0, 0,0,0);\
      o1 = __builtin_amdgcn_mfma_f32_32x32x16_f16(pfr[ks], kt1[ks], o1, 0,0,0);\
    }                                                                         \
    __builtin_amdgcn_s_setprio(0);                                            \
  }

  for (int jt = 0; jt < 32; jt += 2) {
    // prefetch tile B (jt+1) while processing tile A (jt)
#pragma unroll
    for (int ks = 0; ks < 4; ++ks) {
      qB0[ks] = *reinterpret_cast<const f16x8*>(
          qpp + ((size_t)(jt + 1) * 8 + ks) * 512);
      qB1[ks] = *reinterpret_cast<const f16x8*>(
          qpp + ((size_t)(jt + 1) * 8 + 4 + ks) * 512);
    }
    PROCESS_TILE(qA0, qA1, jt)
    if (jt + 2 < 32) {
#pragma unroll
      for (int ks = 0; ks < 4; ++ks) {
        qA0[ks] = *reinterpret_cast<const f16x8*>(
            qpp + ((size_t)(jt + 2) * 8 + ks) * 512);
        qA1[ks] = *reinterpret_cast<const f16x8*>(
            qpp + ((size_t)(jt + 2) * 8 + 4 + ks) * 512);
      }
    }
    PROCESS_TILE(qB0, qB1, jt + 1)
  }
#undef PROCESS_TILE

  // ---- finalize: combine lsum across lane halves, divide, store ----
  lsl[w][l31] = ls + __shfl_xor(ls, 32);
  __syncthreads();
#pragma unroll
  for (int r = 0; r < 16; ++r) {
    const int il = (r & 3) + 8 * (r >> 2) + 4 * hi;
    const float inv = 1.0f / lsl[w][il];
    const size_t rowb = ((size_t)bh * NTOK + i0 + il) * HD;
    out[rowb + l31]      = o0[r] * inv;
    out[rowb + 32 + l31] = o1[r] * inv;
  }
}

extern "C" void kernel_launch(void* const* d_in, const int* in_sizes, int n_in,
                              void* d_out, int out_size, void* d_ws, size_t ws_size,
                              hipStream_t stream) {
  const float* x  = (const float*)d_in[0];
  const float* Wk = (const float*)d_in[1];
  const float* Wq = (const float*)d_in[2];
  // d_in[3] (Wv) is dead code in the reference — never read.
  float* out = (float*)d_out;

  // ws (f16 elems): [xb|Qp: 8388608][Wkb: 1048576][Wqb: 1048576]
  //                 [Kb: 8388608][Qb|KTp: 8388608]  = 54.5 MB total
  // xb dead after gemm -> Qp; Qb dead after pack_rows -> KTp.
  _Float16* xb  = (_Float16*)d_ws;
  _Float16* Qp  = xb;
  _Float16* Wkb = xb + (size_t)8388608;
  _Float16* Wqb = Wkb + (size_t)1048576;
  _Float16* Kb  = Wqb + (size_t)1048576;
  _Float16* Qb  = Kb + (size_t)8388608;
  _Float16* KTp = Qb;

  cvt_f32_f16<<<8192, 256, 0, stream>>>(x, xb, 2097152, 1.0f);
  cvt_f32_f16<<<1024, 256, 0, stream>>>(Wk, Wkb, 262144, 1.0f);
  // log2(e) folded into Wq so softmax can use exp2 directly
  cvt_f32_f16<<<1024, 256, 0, stream>>>(Wq, Wqb, 262144, 1.4426950408889634f);

  dim3 ggrid(MROWS / 128, DMODEL / 128, 2);
  gemm_f16<<<ggrid, 256, 0, stream>>>(xb, Wkb, Wqb, Kb, Qb);

  pack_rows<<<2048, 256, 0, stream>>>(Qb, Qp);   // Qb -> Qp (into xb space)
  pack_kt<<<2048, 256, 0, stream>>>(Kb, KTp);    // Kb -> KTp (into Qb space)

  attn_mfma<<<1024, 256, 0, stream>>>(Kb, Qp, KTp, out);
}

// Round 9
// 187.101 us; speedup vs baseline: 11.5047x; 1.0315x over previous
//
#include <hip/hip_runtime.h>
#include <cstdint>
#include <cstddef>

#define NTOK 2048
#define DMODEL 1024
#define HD 64
#define MROWS 8192

using f16x8  = __attribute__((ext_vector_type(8))) _Float16;
using f16x4  = __attribute__((ext_vector_type(4))) _Float16;
using f32x4  = __attribute__((ext_vector_type(4))) float;
using f32x16 = __attribute__((ext_vector_type(16))) float;
using u16x8  = __attribute__((ext_vector_type(8))) unsigned short;
using u32x4  = __attribute__((ext_vector_type(4))) unsigned int;

#define Z16 {0.f,0.f,0.f,0.f,0.f,0.f,0.f,0.f,0.f,0.f,0.f,0.f,0.f,0.f,0.f,0.f}

__device__ __forceinline__ unsigned pkf16(float a, float b) {
  return __builtin_bit_cast(unsigned, __builtin_amdgcn_cvt_pkrtz(a, b));
}
__device__ __forceinline__ void plswap(unsigned &a, unsigned &b) {
  auto r = __builtin_amdgcn_permlane32_swap(a, b, false, false);
  a = r[0]; b = r[1];
}
// raw v_exp_f32: args always <= 0; flush-to-zero below -126 is correct for
// softmax tails.
__device__ __forceinline__ float fexp2(float x) {
  return __builtin_amdgcn_exp2f(x);
}

// ---------------------------------------------------------------------------
// f32 -> f16 convert, x (scale=1)
// ---------------------------------------------------------------------------
__global__ __launch_bounds__(256) void cvt_f32_f16(const float* __restrict__ in,
                                                   _Float16* __restrict__ out,
                                                   int n4, float scale) {
  int idx = blockIdx.x * 256 + threadIdx.x;
  if (idx < n4) {
    float4 v = reinterpret_cast<const float4*>(in)[idx];
    f16x4 o;
    o.x = (_Float16)(v.x * scale); o.y = (_Float16)(v.y * scale);
    o.z = (_Float16)(v.z * scale); o.w = (_Float16)(v.w * scale);
    reinterpret_cast<f16x4*>(out)[idx] = o;
  }
}

// both weight matrices in one launch; log2(e) folded into Wq
__global__ __launch_bounds__(256) void cvt_w(const float* __restrict__ Wk,
                                             const float* __restrict__ Wq,
                                             _Float16* __restrict__ Wkb,
                                             _Float16* __restrict__ Wqb) {
  const int idx = blockIdx.x * 256 + threadIdx.x;
  const float* in = blockIdx.y ? Wq : Wk;
  _Float16* out = blockIdx.y ? Wqb : Wkb;
  const float scale = blockIdx.y ? 1.4426950408889634f : 1.0f;
  float4 v = reinterpret_cast<const float4*>(in)[idx];
  f16x4 o;
  o.x = (_Float16)(v.x * scale); o.y = (_Float16)(v.y * scale);
  o.z = (_Float16)(v.z * scale); o.w = (_Float16)(v.w * scale);
  reinterpret_cast<f16x4*>(out)[idx] = o;
}

// ---------------------------------------------------------------------------
// f16 MFMA GEMM: Y[m][o] = sum_k X[m][k] * W[o][k]  (NT), Y stored f16.
// ---------------------------------------------------------------------------
#define GLDS16(g, l) __builtin_amdgcn_global_load_lds(                      \
    (const __attribute__((address_space(1))) void*)(g),                     \
    (__attribute__((address_space(3))) void*)(l), 16, 0, 0)

__global__ __launch_bounds__(256) void gemm_f16(
    const _Float16* __restrict__ X,
    const _Float16* __restrict__ Wk,
    const _Float16* __restrict__ Wq,
    _Float16* __restrict__ Kb,
    _Float16* __restrict__ Qb) {
  const _Float16* __restrict__ W = blockIdx.z ? Wq : Wk;
  _Float16* __restrict__ Y = blockIdx.z ? Qb : Kb;

  __shared__ _Float16 As[2][128 * 32];
  __shared__ _Float16 Bs[2][128 * 32];

  const int tid = threadIdx.x;
  const int lane = tid & 63;
  const int w = tid >> 6;
  const int m0 = blockIdx.x * 128;
  const int o0 = blockIdx.y * 128;

  const int srow = w * 32 + (lane >> 2);
  const int scol = (lane & 3) * 8;
  const _Float16* xsrc = X + (size_t)(m0 + srow) * DMODEL + scol;
  const _Float16* wsrc = W + (size_t)(o0 + srow) * DMODEL + scol;

  const int wr = w >> 1, wc = w & 1;
  const int arow = lane & 15, kg = lane >> 4;

  f32x4 zero = {0.f, 0.f, 0.f, 0.f};
  f32x4 acc[4][4];
#pragma unroll
  for (int mi = 0; mi < 4; ++mi)
#pragma unroll
    for (int ni = 0; ni < 4; ++ni) acc[mi][ni] = zero;

  GLDS16(xsrc,               &As[0][(w * 32) * 32]);
  GLDS16(xsrc + 16 * DMODEL, &As[0][(w * 32 + 16) * 32]);
  GLDS16(wsrc,               &Bs[0][(w * 32) * 32]);
  GLDS16(wsrc + 16 * DMODEL, &Bs[0][(w * 32 + 16) * 32]);

  for (int kt = 0; kt < 32; ++kt) {
    __syncthreads();
    if (kt + 1 < 32) {
      const int ko = (kt + 1) * 32;
      const int bn = (kt + 1) & 1;
      GLDS16(xsrc + ko,               &As[bn][(w * 32) * 32]);
      GLDS16(xsrc + ko + 16 * DMODEL, &As[bn][(w * 32 + 16) * 32]);
      GLDS16(wsrc + ko,               &Bs[bn][(w * 32) * 32]);
      GLDS16(wsrc + ko + 16 * DMODEL, &Bs[bn][(w * 32 + 16) * 32]);
    }
    const int buf = kt & 1;
    f16x8 af[4], bfr[4];
#pragma unroll
    for (int mi = 0; mi < 4; ++mi)
      af[mi] = *reinterpret_cast<const f16x8*>(
          &As[buf][(wr * 64 + mi * 16 + arow) * 32 + kg * 8]);
#pragma unroll
    for (int ni = 0; ni < 4; ++ni)
      bfr[ni] = *reinterpret_cast<const f16x8*>(
          &Bs[buf][(wc * 64 + ni * 16 + arow) * 32 + kg * 8]);
#pragma unroll
    for (int mi = 0; mi < 4; ++mi)
#pragma unroll
      for (int ni = 0; ni < 4; ++ni)
        acc[mi][ni] = __builtin_amdgcn_mfma_f32_16x16x32_f16(
            af[mi], bfr[ni], acc[mi][ni], 0, 0, 0);
  }

#pragma unroll
  for (int mi = 0; mi < 4; ++mi) {
#pragma unroll
    for (int ni = 0; ni < 4; ++ni) {
#pragma unroll
      for (int r = 0; r < 4; ++r) {
        const int m = m0 + wr * 64 + mi * 16 + kg * 4 + r;
        const int o = o0 + wc * 64 + ni * 16 + arow;
        Y[(size_t)m * DMODEL + o] = (_Float16)acc[mi][ni][r];
      }
    }
  }
}

// ---------------------------------------------------------------------------
// Combined pack kernel (grid.y: 0 = pack Q rows, 1 = pack K transposed).
// y=0: Qp[bh][rt(32-row tiles)][ks][lane][8]  = Q_head[rt*32+(l&31)][ks*16+(l>>5)*8+e]
// y=1: KTp[bh][jt][ds][ks][lane][8] = K_head[jt*64+ks*16+(l>>5)*8+e][ds*32+(l&31)]
// Both stage a 64x64 head-tile through padded LDS; all phases coalesced.
// ---------------------------------------------------------------------------
__global__ __launch_bounds__(256) void pack_qkt(
    const _Float16* __restrict__ Qb,
    const _Float16* __restrict__ Kb,
    _Float16* __restrict__ Qp,
    _Float16* __restrict__ KTp) {
  const int blk = blockIdx.x;
  const int bh = blk >> 5;
  const int t64 = blk & 31;
  const int b = bh >> 4, h = bh & 15;
  const int tid = threadIdx.x;
  const _Float16* Src = blockIdx.y ? Kb : Qb;

  __shared__ _Float16 t[64][72];
#pragma unroll
  for (int rr = 0; rr < 2; ++rr) {
    const int c = tid + rr * 256;
    const int jr = c >> 3, dcol = (c & 7) * 8;
    *reinterpret_cast<f16x8*>(&t[jr][dcol]) =
        *reinterpret_cast<const f16x8*>(
            &Src[(size_t)(b * NTOK + t64 * 64 + jr) * DMODEL + h * HD + dcol]);
  }
  __syncthreads();
  if (blockIdx.y == 0) {
#pragma unroll
    for (int rr = 0; rr < 2; ++rr) {
      const int cI = tid + rr * 256;   // (rs,ks,l)
      const int rs = cI >> 8, ks = (cI >> 6) & 3, l = cI & 63;
      f16x8 v = *reinterpret_cast<const f16x8*>(
          &t[rs * 32 + (l & 31)][ks * 16 + (l >> 5) * 8]);
      const size_t ch = ((size_t)(bh * 64 + t64 * 2 + rs) * 4 + ks) * 512 + l * 8;
      *reinterpret_cast<f16x8*>(&Qp[ch]) = v;
    }
  } else {
#pragma unroll
    for (int rr = 0; rr < 2; ++rr) {
      const int cI = tid + rr * 256;   // (ds,ks,l)
      const int ds = cI >> 8, ks = (cI >> 6) & 3, l = cI & 63;
      const int col = ds * 32 + (l & 31);
      const int row0 = ks * 16 + (l >> 5) * 8;
      f16x8 v;
#pragma unroll
      for (int e = 0; e < 8; ++e) v[e] = t[row0 + e][col];
      const size_t ch = (((size_t)(bh * 32 + t64) * 2 + ds) * 4 + ks) * 512 + l * 8;
      *reinterpret_cast<f16x8*>(&KTp[ch]) = v;
    }
  }
}

// ---------------------------------------------------------------------------
// Swapped-operand MFMA flash attention, T15 double-pipeline, PACKED operands.
// Two S-tiles live (sA/sB named ping-pong): QK(t+1) is issued in program
// order BEFORE softmax(t)+PV(t), so the MFMA pipe computes tile t+1's scores
// while the VALU runs tile t's softmax (separate pipes, m114).
// Per tile: in-register softmax (defer-max THR=8, per-row rescale routed
// via LDS scl line); P repacked in-register (cvt_pkrtz+permlane32_swap);
// O += mfma(P, KT). All loads lane -> base + lane*16B (coalesced).
// ---------------------------------------------------------------------------
__global__ __launch_bounds__(256) void attn_mfma(
    const _Float16* __restrict__ Kb,
    const _Float16* __restrict__ Qp,
    const _Float16* __restrict__ KTp,
    float* __restrict__ out) {
  const int bid = blockIdx.x;
  const int myid = (bid & 7) * 128 + (bid >> 3);   // 1024 blocks, bijective
  const int bh = myid >> 4;
  const int itile = myid & 15;
  const int b = bh >> 4, h = bh & 15;
  const int tid = threadIdx.x, lane = tid & 63, w = tid >> 6;
  const int l31 = lane & 31;
  const int hi = lane >> 5;
  const int hi8 = hi * 8;
  const int i0 = itile * 128 + w * 32;

  const _Float16* Kh   = Kb + (size_t)b * NTOK * DMODEL + h * HD;
  const _Float16* qpp  = Qp  + (size_t)bh * 131072 + lane * 8;
  const _Float16* ktpp = KTp + (size_t)bh * 131072 + lane * 8;

  __shared__ float lsl[4][32];
  __shared__ float scl[4][32];

  // kbf: one-time per wave (uncoalesced but tiny)
  f16x8 kbf[4];
#pragma unroll
  for (int ks = 0; ks < 4; ++ks)
    kbf[ks] = *reinterpret_cast<const f16x8*>(
        &Kh[(size_t)(i0 + l31) * DMODEL + ks * 16 + hi8]);

  const f32x16 z16v = Z16;
  f32x16 o0 = z16v, o1 = z16v;
  float mreg = -1e30f, ls = 0.f;

  f16x8 qA0[4], qA1[4], qB0[4], qB1[4];
  f32x16 sA0, sA1, sB0, sB1;

#define LOADQ(QD0, QD1, JT)                                                   \
  _Pragma("unroll")                                                           \
  for (int ks = 0; ks < 4; ++ks) {                                            \
    QD0[ks] = *reinterpret_cast<const f16x8*>(                                \
        qpp + ((size_t)(JT) * 8 + ks) * 512);                                 \
    QD1[ks] = *reinterpret_cast<const f16x8*>(                                \
        qpp + ((size_t)(JT) * 8 + 4 + ks) * 512);                             \
  }

#define QK_TILE(SD0, SD1, Q0, Q1)                                             \
  SD0 = z16v; SD1 = z16v;                                                     \
  __builtin_amdgcn_s_setprio(1);                                              \
  _Pragma("unroll")                                                           \
  for (int ks = 0; ks < 4; ++ks) {                                            \
    SD0 = __builtin_amdgcn_mfma_f32_32x32x16_f16(Q0[ks], kbf[ks], SD0, 0,0,0);\
    SD1 = __builtin_amdgcn_mfma_f32_32x32x16_f16(Q1[ks], kbf[ks], SD1, 0,0,0);\
  }                                                                           \
  __builtin_amdgcn_s_setprio(0);

#define SMPV_TILE(S0, S1, JT)                                                 \
  {                                                                           \
    /* KT loads for THIS tile first: softmax VALU hides their latency */      \
    f16x8 kt0[4], kt1[4];                                                     \
    _Pragma("unroll")                                                         \
    for (int ks = 0; ks < 4; ++ks) {                                          \
      kt0[ks] = *reinterpret_cast<const f16x8*>(                              \
          ktpp + ((size_t)(JT) * 8 + ks) * 512);                              \
      kt1[ks] = *reinterpret_cast<const f16x8*>(                              \
          ktpp + ((size_t)(JT) * 8 + 4 + ks) * 512);                          \
    }                                                                         \
    float m0 = fmaxf(S0[0], S1[0]);                                           \
    float m1 = fmaxf(S0[1], S1[1]);                                           \
    float m2 = fmaxf(S0[2], S1[2]);                                           \
    float m3 = fmaxf(S0[3], S1[3]);                                           \
    _Pragma("unroll")                                                         \
    for (int r = 4; r < 16; r += 4) {                                         \
      m0 = fmaxf(m0, fmaxf(S0[r], S1[r]));                                    \
      m1 = fmaxf(m1, fmaxf(S0[r + 1], S1[r + 1]));                            \
      m2 = fmaxf(m2, fmaxf(S0[r + 2], S1[r + 2]));                            \
      m3 = fmaxf(m3, fmaxf(S0[r + 3], S1[r + 3]));                            \
    }                                                                         \
    float pm = fmaxf(fmaxf(m0, m1), fmaxf(m2, m3));                           \
    pm = fmaxf(pm, __shfl_xor(pm, 32));                                       \
    if (!__all(pm <= mreg + 8.0f)) {                                          \
      const float mn = fmaxf(mreg, pm);                                       \
      const float sc = fexp2(mreg - mn);                                      \
      ls *= sc;                                                               \
      mreg = mn;                                                              \
      scl[w][l31] = sc;                                                       \
      _Pragma("unroll")                                                       \
      for (int r = 0; r < 16; ++r) {                                          \
        const int il = (r & 3) + 8 * (r >> 2) + 4 * hi;                       \
        const float scr = scl[w][il];                                         \
        o0[r] *= scr; o1[r] *= scr;                                           \
      }                                                                       \
    }                                                                         \
    float p0a[16], p1a[16];                                                   \
    _Pragma("unroll")                                                         \
    for (int r = 0; r < 16; ++r) {                                            \
      p0a[r] = fexp2(S0[r] - mreg);                                           \
      p1a[r] = fexp2(S1[r] - mreg);                                           \
    }                                                                         \
    float l0 = 0.f, l1 = 0.f, l2 = 0.f, l3 = 0.f;                             \
    _Pragma("unroll")                                                         \
    for (int r = 0; r < 16; r += 4) {                                         \
      l0 += p0a[r]     + p1a[r];                                              \
      l1 += p0a[r + 1] + p1a[r + 1];                                          \
      l2 += p0a[r + 2] + p1a[r + 2];                                          \
      l3 += p0a[r + 3] + p1a[r + 3];                                          \
    }                                                                         \
    ls += (l0 + l1) + (l2 + l3);                                              \
    f16x8 pfr[4];                                                             \
    {                                                                         \
      unsigned a0 = pkf16(p0a[0], p0a[1]),  b0 = pkf16(p0a[4], p0a[5]);       \
      unsigned a1 = pkf16(p0a[2], p0a[3]),  b1 = pkf16(p0a[6], p0a[7]);       \
      plswap(a0, b0); plswap(a1, b1);                                         \
      u32x4 t; t[0] = a0; t[1] = a1; t[2] = b0; t[3] = b1;                    \
      pfr[0] = __builtin_bit_cast(f16x8, t);                                  \
      unsigned a2 = pkf16(p0a[8], p0a[9]),   b2 = pkf16(p0a[12], p0a[13]);    \
      unsigned a3 = pkf16(p0a[10], p0a[11]), b3 = pkf16(p0a[14], p0a[15]);    \
      plswap(a2, b2); plswap(a3, b3);                                         \
      t[0] = a2; t[1] = a3; t[2] = b2; t[3] = b3;                             \
      pfr[1] = __builtin_bit_cast(f16x8, t);                                  \
      unsigned a4 = pkf16(p1a[0], p1a[1]),  b4 = pkf16(p1a[4], p1a[5]);       \
      unsigned a5 = pkf16(p1a[2], p1a[3]),  b5 = pkf16(p1a[6], p1a[7]);       \
      plswap(a4, b4); plswap(a5, b5);                                         \
      t[0] = a4; t[1] = a5; t[2] = b4; t[3] = b5;                             \
      pfr[2] = __builtin_bit_cast(f16x8, t);                                  \
      unsigned a6 = pkf16(p1a[8], p1a[9]),   b6 = pkf16(p1a[12], p1a[13]);    \
      unsigned a7 = pkf16(p1a[10], p1a[11]), b7 = pkf16(p1a[14], p1a[15]);    \
      plswap(a6, b6); plswap(a7, b7);                                         \
      t[0] = a6; t[1] = a7; t[2] = b6; t[3] = b7;                             \
      pfr[3] = __builtin_bit_cast(f16x8, t);                                  \
    }                                                                         \
    __builtin_amdgcn_s_setprio(1);                                            \
    _Pragma("unroll")                                                         \
    for (int ks = 0; ks < 4; ++ks) {                                          \
      o0 = __builtin_amdgcn_mfma_f32_32x32x16_f16(pfr[ks], kt0[ks], o0, 0,0,0);\
      o1 = __builtin_amdgcn_mfma_f32_32x32x16_f16(pfr[ks], kt1[ks], o1, 0,0,0);\
    }                                                                         \
    __builtin_amdgcn_s_setprio(0);                                            \
  }

  // prologue: tile 0 scores in sA, tile 1 Q in qB
  LOADQ(qA0, qA1, 0)
  QK_TILE(sA0, sA1, qA0, qA1)
  LOADQ(qB0, qB1, 1)

  for (int jt = 0; jt < 30; jt += 2) {
    QK_TILE(sB0, sB1, qB0, qB1)      // tile jt+1 scores (MFMA ∥ sm below)
    LOADQ(qA0, qA1, jt + 2)
    SMPV_TILE(sA0, sA1, jt)
    QK_TILE(sA0, sA1, qA0, qA1)      // tile jt+2 scores
    LOADQ(qB0, qB1, jt + 3)
    SMPV_TILE(sB0, sB1, jt + 1)
  }
  // tail: jt = 30; sA holds tile 30, qB holds tile 31's Q
  QK_TILE(sB0, sB1, qB0, qB1)
  SMPV_TILE(sA0, sA1, 30)
  SMPV_TILE(sB0, sB1, 31)

#undef LOADQ
#undef QK_TILE
#undef SMPV_TILE

  // ---- finalize: combine lsum across lane halves, divide, store ----
  lsl[w][l31] = ls + __shfl_xor(ls, 32);
  __syncthreads();
#pragma unroll
  for (int r = 0; r < 16; ++r) {
    const int il = (r & 3) + 8 * (r >> 2) + 4 * hi;
    const float inv = 1.0f / lsl[w][il];
    const size_t rowb = ((size_t)bh * NTOK + i0 + il) * HD;
    out[rowb + l31]      = o0[r] * inv;
    out[rowb + 32 + l31] = o1[r] * inv;
  }
}

extern "C" void kernel_launch(void* const* d_in, const int* in_sizes, int n_in,
                              void* d_out, int out_size, void* d_ws, size_t ws_size,
                              hipStream_t stream) {
  const float* x  = (const float*)d_in[0];
  const float* Wk = (const float*)d_in[1];
  const float* Wq = (const float*)d_in[2];
  // d_in[3] (Wv) is dead code in the reference — never read.
  float* out = (float*)d_out;

  // ws (f16 elems): [xb|Qp: 8388608][Wkb: 1048576][Wqb: 1048576]
  //                 [Kb: 8388608][Qb|KTp: 8388608]
  _Float16* xb  = (_Float16*)d_ws;
  _Float16* Qp  = xb;
  _Float16* Wkb = xb + (size_t)8388608;
  _Float16* Wqb = Wkb + (size_t)1048576;
  _Float16* Kb  = Wqb + (size_t)1048576;
  _Float16* Qb  = Kb + (size_t)8388608;
  _Float16* KTp = Qb;

  cvt_f32_f16<<<8192, 256, 0, stream>>>(x, xb, 2097152, 1.0f);
  cvt_w<<<dim3(1024, 2), 256, 0, stream>>>(Wk, Wq, Wkb, Wqb);

  dim3 ggrid(MROWS / 128, DMODEL / 128, 2);
  gemm_f16<<<ggrid, 256, 0, stream>>>(xb, Wkb, Wqb, Kb, Qb);

  pack_qkt<<<dim3(2048, 2), 256, 0, stream>>>(Qb, Kb, Qp, KTp);

  attn_mfma<<<1024, 256, 0, stream>>>(Kb, Qp, KTp, out);
}